// Round 1
// baseline (843.524 us; speedup 1.0000x reference)
//
#include <hip/hip_runtime.h>
#include <math.h>

#define NEG_SLOPE 0.2f
#define EPSV 1e-16f

// ---------------- CSR build ----------------

__global__ void k_zero(int* p, int n){
    int i = blockIdx.x * blockDim.x + threadIdx.x;
    if (i < n) p[i] = 0;
}

__global__ void k_hist(const int* __restrict__ ei, int E, int ET, int* __restrict__ deg){
    int i = blockIdx.x * blockDim.x + threadIdx.x;
    if (i < ET){
        int dst = (i < E) ? ei[E + i] : (i - E);   // self loops appended
        atomicAdd(&deg[dst], 1);
    }
}

// single-block exclusive scan (N=50k, 1024 threads, ~49 chunks)
__global__ void k_scan(const int* __restrict__ deg, int* __restrict__ rowptr,
                       int* __restrict__ cursor, int N){
    __shared__ int wsum[16];
    __shared__ int ctot;
    int t = threadIdx.x, lane = t & 63, wid = t >> 6;
    int running = 0;
    for (int base = 0; base < N; base += 1024){
        int i = base + t;
        int v = (i < N) ? deg[i] : 0;
        int x = v;
        #pragma unroll
        for (int off = 1; off < 64; off <<= 1){
            int y = __shfl_up(x, off, 64);
            if (lane >= off) x += y;
        }
        if (lane == 63) wsum[wid] = x;
        __syncthreads();
        if (wid == 0){
            int w = (lane < 16) ? wsum[lane] : 0;
            #pragma unroll
            for (int off = 1; off < 16; off <<= 1){
                int y = __shfl_up(w, off, 64);
                if (lane >= off) w += y;
            }
            if (lane < 16) wsum[lane] = w;
            if (lane == 15) ctot = w;
        }
        __syncthreads();
        int woff = wid ? wsum[wid - 1] : 0;
        int incl = x + woff;
        int excl = running + incl - v;
        if (i < N){ rowptr[i] = excl; cursor[i] = excl; }
        if (i == N - 1) rowptr[N] = excl + v;
        running += ctot;
        __syncthreads();
    }
}

__global__ void k_scatter(const int* __restrict__ ei, int E, int ET,
                          int* __restrict__ cursor, int* __restrict__ csr_src){
    int i = blockIdx.x * blockDim.x + threadIdx.x;
    if (i < ET){
        int s, d;
        if (i < E){ s = ei[i]; d = ei[E + i]; } else { s = i - E; d = s; }
        int pos = atomicAdd(&cursor[d], 1);
        csr_src[pos] = s;
    }
}

// ---------------- GEMM1: h1 = x @ W1 (+ alpha epilogue on half==1) ----------------
// half-K (64 rows of W1, 32 KB) staged in LDS once per block; 2 nodes per iter.

__launch_bounds__(256)
__global__ void k_gemm1(const float* __restrict__ x, const float* __restrict__ W1,
                        const float* __restrict__ a_src, const float* __restrict__ a_dst,
                        float* __restrict__ h1, float* __restrict__ asrc1,
                        float* __restrict__ adst1, int N, int half){
    __shared__ float Wl[64 * 128];
    __shared__ float xl[2][64];
    int t = threadIdx.x;
    int sub = t >> 7, col = t & 127;
    for (int idx = t; idx < 64 * 128; idx += 256) Wl[idx] = W1[half * 64 * 128 + idx];
    __syncthreads();
    for (int np = blockIdx.x; np * 2 < N; np += gridDim.x){
        int n0 = np * 2;
        if (t < 128){
            int nn = t >> 6, k = t & 63;
            xl[nn][k] = x[(size_t)(n0 + nn) * 128 + half * 64 + k];
        }
        __syncthreads();
        float acc = (half == 0) ? 0.f : h1[(size_t)(n0 + sub) * 128 + col];
        #pragma unroll
        for (int k = 0; k < 64; k++)
            acc += xl[sub][k] * Wl[k * 128 + col];
        h1[(size_t)(n0 + sub) * 128 + col] = acc;
        if (half == 1){
            int hh = col >> 5, c = col & 31;
            float vs = acc * a_src[hh * 32 + c];
            float vd = acc * a_dst[hh * 32 + c];
            #pragma unroll
            for (int m = 16; m >= 1; m >>= 1){
                vs += __shfl_xor(vs, m, 32);
                vd += __shfl_xor(vd, m, 32);
            }
            if (c == 0){
                asrc1[(n0 + sub) * 4 + hh] = vs;
                adst1[(n0 + sub) * 4 + hh] = vd;
            }
        }
        __syncthreads();
    }
}

// ---------------- Aggregation layer 1 (block per dst node, 128 thr) ----------------

__launch_bounds__(128)
__global__ void k_agg1(const int* __restrict__ rowptr, const int* __restrict__ csr_src,
                       const float* __restrict__ h1,
                       const float* __restrict__ asrc1, const float* __restrict__ adst1,
                       const float* __restrict__ b1, float* __restrict__ x2){
    int n = blockIdx.x;
    int t = threadIdx.x;
    int hh = t >> 5;
    int start = rowptr[n], end = rowptr[n + 1];
    float adn = adst1[n * 4 + hh];
    float mx = -1e30f;
    for (int i = start; i < end; i++){
        int s = csr_src[i];
        float e = asrc1[s * 4 + hh] + adn;
        e = (e > 0.f) ? e : NEG_SLOPE * e;
        mx = fmaxf(mx, e);
    }
    float ssum = 0.f, acc = 0.f;
    for (int i = start; i < end; i++){
        int s = csr_src[i];
        float e = asrc1[s * 4 + hh] + adn;
        e = (e > 0.f) ? e : NEG_SLOPE * e;
        float ex = __expf(e - mx);
        ssum += ex;
        acc += ex * h1[(size_t)s * 128 + t];
    }
    float o = acc / (ssum + EPSV) + b1[t];
    x2[(size_t)n * 128 + t] = (o > 0.f) ? o : expm1f(o);   // ELU fused
}

// ---------------- GEMM2: h2 = x2 @ W2 (+ alpha2 epilogue) ----------------

__launch_bounds__(256)
__global__ void k_gemm2(const float* __restrict__ x2, const float* __restrict__ W2,
                        const float* __restrict__ a_src, const float* __restrict__ a_dst,
                        float* __restrict__ h2, float* __restrict__ asrc2,
                        float* __restrict__ adst2, int N){
    __shared__ float Wl[128 * 32];
    __shared__ float xl[8 * 128];
    int t = threadIdx.x;
    int sub = t >> 5, c = t & 31;
    for (int idx = t; idx < 128 * 32; idx += 256) Wl[idx] = W2[idx];
    __syncthreads();
    for (int nb = blockIdx.x; nb * 8 < N; nb += gridDim.x){
        int n0 = nb * 8;
        for (int idx = t; idx < 1024; idx += 256) xl[idx] = x2[(size_t)n0 * 128 + idx];
        __syncthreads();
        float acc = 0.f;
        #pragma unroll
        for (int k = 0; k < 128; k++)
            acc += xl[sub * 128 + k] * Wl[k * 32 + c];
        int n = n0 + sub;
        h2[(size_t)n * 32 + c] = acc;
        float vs = acc * a_src[c], vd = acc * a_dst[c];
        #pragma unroll
        for (int m = 16; m >= 1; m >>= 1){
            vs += __shfl_xor(vs, m, 32);
            vd += __shfl_xor(vd, m, 32);
        }
        if (c == 0){ asrc2[n] = vs; adst2[n] = vd; }
        __syncthreads();
    }
}

// ---------------- Aggregation layer 2 (2 nodes per 64-thr block) ----------------

__launch_bounds__(64)
__global__ void k_agg2(const int* __restrict__ rowptr, const int* __restrict__ csr_src,
                       const float* __restrict__ h2,
                       const float* __restrict__ asrc2, const float* __restrict__ adst2,
                       const float* __restrict__ b2, float* __restrict__ out){
    int t = threadIdx.x;
    int n = blockIdx.x * 2 + (t >> 5);
    int c = t & 31;
    int start = rowptr[n], end = rowptr[n + 1];
    float adn = adst2[n];
    float mx = -1e30f;
    for (int i = start; i < end; i++){
        int s = csr_src[i];
        float e = asrc2[s] + adn;
        e = (e > 0.f) ? e : NEG_SLOPE * e;
        mx = fmaxf(mx, e);
    }
    float ssum = 0.f, acc = 0.f;
    for (int i = start; i < end; i++){
        int s = csr_src[i];
        float e = asrc2[s] + adn;
        e = (e > 0.f) ? e : NEG_SLOPE * e;
        float ex = __expf(e - mx);
        ssum += ex;
        acc += ex * h2[(size_t)s * 32 + c];
    }
    out[(size_t)n * 32 + c] = acc / (ssum + EPSV) + b2[c];
}

// ---------------- launch ----------------

extern "C" void kernel_launch(void* const* d_in, const int* in_sizes, int n_in,
                              void* d_out, int out_size, void* d_ws, size_t ws_size,
                              hipStream_t stream){
    const float* x      = (const float*)d_in[0];
    const int*   ei     = (const int*)  d_in[1];
    const float* W1     = (const float*)d_in[2];
    const float* a_src1 = (const float*)d_in[3];
    const float* a_dst1 = (const float*)d_in[4];
    const float* b1     = (const float*)d_in[5];
    const float* W2     = (const float*)d_in[6];
    const float* a_src2 = (const float*)d_in[7];
    const float* a_dst2 = (const float*)d_in[8];
    const float* b2     = (const float*)d_in[9];
    float* out = (float*)d_out;

    int N  = in_sizes[0] / 128;
    int E  = in_sizes[1] / 2;
    int ET = E + N;

    char* ws = (char*)d_ws;
    size_t off = 0;
    auto alloc = [&](size_t bytes) -> char* {
        char* p = ws + off;
        off += (bytes + 255) & ~(size_t)255;
        return p;
    };
    int*   deg     = (int*)  alloc((size_t)N * 4);
    int*   cursor  = (int*)  alloc((size_t)N * 4);
    int*   rowptr  = (int*)  alloc((size_t)(N + 1) * 4);
    int*   csr_src = (int*)  alloc((size_t)ET * 4);
    float* h1      = (float*)alloc((size_t)N * 128 * 4);
    float* x2      = (float*)alloc((size_t)N * 128 * 4);
    float* asrc1   = (float*)alloc((size_t)N * 4 * 4);
    float* adst1   = (float*)alloc((size_t)N * 4 * 4);
    float* h2      = (float*)alloc((size_t)N * 32 * 4);
    float* asrc2   = (float*)alloc((size_t)N * 4);
    float* adst2   = (float*)alloc((size_t)N * 4);

    hipLaunchKernelGGL(k_zero,    dim3((N + 255) / 256),  dim3(256),  0, stream, deg, N);
    hipLaunchKernelGGL(k_hist,    dim3((ET + 255) / 256), dim3(256),  0, stream, ei, E, ET, deg);
    hipLaunchKernelGGL(k_scan,    dim3(1),                dim3(1024), 0, stream, deg, rowptr, cursor, N);
    hipLaunchKernelGGL(k_scatter, dim3((ET + 255) / 256), dim3(256),  0, stream, ei, E, ET, cursor, csr_src);
    hipLaunchKernelGGL(k_gemm1,   dim3(1024), dim3(256), 0, stream, x, W1, a_src1, a_dst1, h1, asrc1, adst1, N, 0);
    hipLaunchKernelGGL(k_gemm1,   dim3(1024), dim3(256), 0, stream, x, W1, a_src1, a_dst1, h1, asrc1, adst1, N, 1);
    hipLaunchKernelGGL(k_agg1,    dim3(N),    dim3(128), 0, stream, rowptr, csr_src, h1, asrc1, adst1, b1, x2);
    hipLaunchKernelGGL(k_gemm2,   dim3(1024), dim3(256), 0, stream, x2, W2, a_src2, a_dst2, h2, asrc2, adst2, N);
    hipLaunchKernelGGL(k_agg2,    dim3(N / 2), dim3(64), 0, stream, rowptr, csr_src, h2, asrc2, adst2, b2, out);
}

// Round 2
// 518.511 us; speedup vs baseline: 1.6268x; 1.6268x over previous
//
#include <hip/hip_runtime.h>
#include <math.h>

#define NEG_SLOPE 0.2f
#define EPSV 1e-16f

// ---------------- CSR build ----------------

__global__ void k_zero(int* p, int n){
    int i = blockIdx.x * blockDim.x + threadIdx.x;
    if (i < n) p[i] = 0;
}

__global__ void k_hist(const int* __restrict__ ei, int E, int ET, int* __restrict__ deg){
    int i = blockIdx.x * blockDim.x + threadIdx.x;
    if (i < ET){
        int dst = (i < E) ? ei[E + i] : (i - E);   // self loops appended
        atomicAdd(&deg[dst], 1);
    }
}

// hierarchical scan: 49 blocks x 1024 elems -> top scan of 49 -> fixup
__global__ void k_scan_blk(const int* __restrict__ deg, int N,
                           int* __restrict__ rowptr, int* __restrict__ bsum){
    int b = blockIdx.x, t = threadIdx.x;
    int base = b * 1024 + t * 4;
    int v[4];
    #pragma unroll
    for (int j = 0; j < 4; j++) v[j] = (base + j < N) ? deg[base + j] : 0;
    int s = v[0] + v[1] + v[2] + v[3];
    int lane = t & 63, wid = t >> 6;
    int x = s;
    #pragma unroll
    for (int off = 1; off < 64; off <<= 1){
        int y = __shfl_up(x, off, 64);
        if (lane >= off) x += y;
    }
    __shared__ int ws[4];
    if (lane == 63) ws[wid] = x;
    __syncthreads();
    int woff = 0;
    for (int w = 0; w < wid; w++) woff += ws[w];
    int run = woff + x - s;
    #pragma unroll
    for (int j = 0; j < 4; j++){
        if (base + j < N) rowptr[base + j] = run;
        run += v[j];
    }
    if (t == 255) bsum[b] = woff + x;
}

__global__ void k_scan_top(int* bsum, int nb){
    int t = threadIdx.x;
    int v = (t < nb) ? bsum[t] : 0;
    int x = v;
    #pragma unroll
    for (int off = 1; off < 64; off <<= 1){
        int y = __shfl_up(x, off, 64);
        if (t >= off) x += y;
    }
    if (t < nb) bsum[t] = x - v;   // exclusive
}

__global__ void k_scan_add(const int* __restrict__ bsum, int N, int ET,
                           int* __restrict__ rowptr, int* __restrict__ cursor){
    int b = blockIdx.x, t = threadIdx.x;
    int off = bsum[b];
    int base = b * 1024 + t * 4;
    #pragma unroll
    for (int j = 0; j < 4; j++){
        if (base + j < N){
            int r = rowptr[base + j] + off;
            rowptr[base + j] = r;
            cursor[base + j] = r;
        }
    }
    if (b == 0 && t == 0) rowptr[N] = ET;
}

__global__ void k_scatter(const int* __restrict__ ei, int E, int ET,
                          int* __restrict__ cursor, int* __restrict__ csr_src){
    int i = blockIdx.x * blockDim.x + threadIdx.x;
    if (i < ET){
        int s, d;
        if (i < E){ s = ei[i]; d = ei[E + i]; } else { s = i - E; d = s; }
        int pos = atomicAdd(&cursor[d], 1);
        csr_src[pos] = s;
    }
}

// ---------------- GEMM1: h1 = x @ W1, fused alpha epilogue ----------------
// 512 thr = 16 node-slots x 32 col-groups; thread computes float4 of cols.
// Full W1 (64 KB) in LDS; 4 FMA per ds_read_b128.

__launch_bounds__(512)
__global__ void k_gemm1(const float* __restrict__ x, const float* __restrict__ W1,
                        const float* __restrict__ a_src, const float* __restrict__ a_dst,
                        float* __restrict__ h1, float* __restrict__ asrc1,
                        float* __restrict__ adst1, int N){
    __shared__ float Wl[128 * 128];   // [k][col]
    __shared__ float xl[16][128];
    int t = threadIdx.x;
    int cg = t & 31, ns = t >> 5;
    for (int idx = t; idx < 128 * 128 / 4; idx += 512)
        *(float4*)&Wl[idx * 4] = *(const float4*)&W1[idx * 4];
    float4 a4s = *(const float4*)&a_src[cg * 4];
    float4 a4d = *(const float4*)&a_dst[cg * 4];
    int n0 = blockIdx.x * 16;
    *(float4*)&xl[ns][cg * 4] = *(const float4*)&x[(size_t)(n0 + ns) * 128 + cg * 4];
    __syncthreads();
    float4 acc = {0.f, 0.f, 0.f, 0.f};
    #pragma unroll 8
    for (int k = 0; k < 128; k++){
        float xs = xl[ns][k];
        float4 w = *(float4*)&Wl[k * 128 + cg * 4];
        acc.x = fmaf(xs, w.x, acc.x);
        acc.y = fmaf(xs, w.y, acc.y);
        acc.z = fmaf(xs, w.z, acc.z);
        acc.w = fmaf(xs, w.w, acc.w);
    }
    int n = n0 + ns;
    *(float4*)&h1[(size_t)n * 128 + cg * 4] = acc;
    float vs = acc.x * a4s.x + acc.y * a4s.y + acc.z * a4s.z + acc.w * a4s.w;
    float vd = acc.x * a4d.x + acc.y * a4d.y + acc.z * a4d.z + acc.w * a4d.w;
    #pragma unroll
    for (int m = 1; m <= 4; m <<= 1){
        vs += __shfl_xor(vs, m, 64);
        vd += __shfl_xor(vd, m, 64);
    }
    if ((cg & 7) == 0){
        int head = cg >> 3;
        asrc1[n * 4 + head] = vs;
        adst1[n * 4 + head] = vd;
    }
}

// ---------------- Aggregation layer 1: single pass, no max ----------------
// e bounded (|e| <~ 5) so exp() is safe without max subtraction; ratio identical.

__launch_bounds__(128)
__global__ void k_agg1(const int* __restrict__ rowptr, const int* __restrict__ csr_src,
                       const float* __restrict__ h1,
                       const float* __restrict__ asrc1, const float* __restrict__ adst1,
                       const float* __restrict__ b1, float* __restrict__ x2){
    int n = blockIdx.x;
    int t = threadIdx.x;
    int hh = t >> 5;
    int start = rowptr[n], end = rowptr[n + 1];
    float adn = adst1[(n << 2) + hh];
    float ssum = 0.f, acc = 0.f;
    int i = start;
    for (; i + 2 <= end; i += 2){
        int s0 = csr_src[i], s1 = csr_src[i + 1];
        float e0 = asrc1[(s0 << 2) + hh] + adn;
        float e1 = asrc1[(s1 << 2) + hh] + adn;
        e0 = fmaxf(e0, NEG_SLOPE * e0);
        e1 = fmaxf(e1, NEG_SLOPE * e1);
        float w0 = __expf(e0);
        float w1 = __expf(e1);
        float g0 = h1[(s0 << 7) + t];
        float g1 = h1[(s1 << 7) + t];
        ssum += w0 + w1;
        acc = fmaf(w0, g0, acc);
        acc = fmaf(w1, g1, acc);
    }
    if (i < end){
        int s0 = csr_src[i];
        float e0 = asrc1[(s0 << 2) + hh] + adn;
        e0 = fmaxf(e0, NEG_SLOPE * e0);
        float w0 = __expf(e0);
        ssum += w0;
        acc = fmaf(w0, h1[(s0 << 7) + t], acc);
    }
    float o = acc / (ssum + EPSV) + b1[t];
    x2[((size_t)n << 7) + t] = (o > 0.f) ? o : expm1f(o);   // ELU fused
}

// ---------------- GEMM2: h2 = x2 @ W2, fused alpha2 epilogue ----------------
// 256 thr = 32 node-slots x 8 col-groups (float4 cols). x-tile padded to 132.

__launch_bounds__(256)
__global__ void k_gemm2(const float* __restrict__ x2, const float* __restrict__ W2,
                        const float* __restrict__ a_src, const float* __restrict__ a_dst,
                        float* __restrict__ h2, float* __restrict__ asrc2,
                        float* __restrict__ adst2, int N){
    __shared__ float Wl[128 * 32];
    __shared__ float xl[32][132];
    int t = threadIdx.x;
    int cg = t & 7, ns = t >> 3;
    for (int idx = t; idx < 1024; idx += 256)
        *(float4*)&Wl[idx * 4] = *(const float4*)&W2[idx * 4];
    int n0 = blockIdx.x * 32;
    for (int idx = t; idx < 1024; idx += 256){
        int nn = idx >> 5, k4 = idx & 31;
        int nn_g = n0 + nn;
        float4 v = {0.f, 0.f, 0.f, 0.f};
        if (nn_g < N) v = *(const float4*)&x2[(size_t)nn_g * 128 + k4 * 4];
        *(float4*)&xl[nn][k4 * 4] = v;
    }
    __syncthreads();
    float4 acc = {0.f, 0.f, 0.f, 0.f};
    #pragma unroll 8
    for (int k = 0; k < 128; k++){
        float xs = xl[ns][k];
        float4 w = *(float4*)&Wl[k * 32 + cg * 4];
        acc.x = fmaf(xs, w.x, acc.x);
        acc.y = fmaf(xs, w.y, acc.y);
        acc.z = fmaf(xs, w.z, acc.z);
        acc.w = fmaf(xs, w.w, acc.w);
    }
    int n = n0 + ns;
    if (n < N){
        *(float4*)&h2[(size_t)n * 32 + cg * 4] = acc;
        float4 a4s = *(const float4*)&a_src[cg * 4];
        float4 a4d = *(const float4*)&a_dst[cg * 4];
        float vs = acc.x * a4s.x + acc.y * a4s.y + acc.z * a4s.z + acc.w * a4s.w;
        float vd = acc.x * a4d.x + acc.y * a4d.y + acc.z * a4d.z + acc.w * a4d.w;
        #pragma unroll
        for (int m = 1; m <= 4; m <<= 1){
            vs += __shfl_xor(vs, m, 64);
            vd += __shfl_xor(vd, m, 64);
        }
        if (cg == 0){ asrc2[n] = vs; adst2[n] = vd; }
    }
}

// ---------------- Aggregation layer 2: 4 nodes per 128-thr block ----------------

__launch_bounds__(128)
__global__ void k_agg2(const int* __restrict__ rowptr, const int* __restrict__ csr_src,
                       const float* __restrict__ h2,
                       const float* __restrict__ asrc2, const float* __restrict__ adst2,
                       const float* __restrict__ b2, float* __restrict__ out){
    int t = threadIdx.x;
    int n = blockIdx.x * 4 + (t >> 5);
    int c = t & 31;
    int start = rowptr[n], end = rowptr[n + 1];
    float adn = adst2[n];
    float ssum = 0.f, acc = 0.f;
    int i = start;
    for (; i + 2 <= end; i += 2){
        int s0 = csr_src[i], s1 = csr_src[i + 1];
        float e0 = asrc2[s0] + adn;
        float e1 = asrc2[s1] + adn;
        e0 = fmaxf(e0, NEG_SLOPE * e0);
        e1 = fmaxf(e1, NEG_SLOPE * e1);
        float w0 = __expf(e0);
        float w1 = __expf(e1);
        float g0 = h2[(s0 << 5) + c];
        float g1 = h2[(s1 << 5) + c];
        ssum += w0 + w1;
        acc = fmaf(w0, g0, acc);
        acc = fmaf(w1, g1, acc);
    }
    if (i < end){
        int s0 = csr_src[i];
        float e0 = asrc2[s0] + adn;
        e0 = fmaxf(e0, NEG_SLOPE * e0);
        float w0 = __expf(e0);
        ssum += w0;
        acc = fmaf(w0, h2[(s0 << 5) + c], acc);
    }
    out[((size_t)n << 5) + c] = acc / (ssum + EPSV) + b2[c];
}

// ---------------- launch ----------------

extern "C" void kernel_launch(void* const* d_in, const int* in_sizes, int n_in,
                              void* d_out, int out_size, void* d_ws, size_t ws_size,
                              hipStream_t stream){
    const float* x      = (const float*)d_in[0];
    const int*   ei     = (const int*)  d_in[1];
    const float* W1     = (const float*)d_in[2];
    const float* a_src1 = (const float*)d_in[3];
    const float* a_dst1 = (const float*)d_in[4];
    const float* b1     = (const float*)d_in[5];
    const float* W2     = (const float*)d_in[6];
    const float* a_src2 = (const float*)d_in[7];
    const float* a_dst2 = (const float*)d_in[8];
    const float* b2     = (const float*)d_in[9];
    float* out = (float*)d_out;

    int N  = in_sizes[0] / 128;
    int E  = in_sizes[1] / 2;
    int ET = E + N;
    int nScanBlk = (N + 1023) / 1024;

    char* ws = (char*)d_ws;
    size_t off = 0;
    auto alloc = [&](size_t bytes) -> char* {
        char* p = ws + off;
        off += (bytes + 255) & ~(size_t)255;
        return p;
    };
    int*   deg     = (int*)  alloc((size_t)N * 4);
    int*   cursor  = (int*)  alloc((size_t)N * 4);
    int*   rowptr  = (int*)  alloc((size_t)(N + 1) * 4);
    int*   bsum    = (int*)  alloc((size_t)nScanBlk * 4);
    int*   csr_src = (int*)  alloc((size_t)ET * 4);
    float* h1      = (float*)alloc((size_t)N * 128 * 4);
    float* x2      = (float*)alloc((size_t)N * 128 * 4);
    float* asrc1   = (float*)alloc((size_t)N * 4 * 4);
    float* adst1   = (float*)alloc((size_t)N * 4 * 4);
    float* h2      = (float*)alloc((size_t)N * 32 * 4);
    float* asrc2   = (float*)alloc((size_t)N * 4);
    float* adst2   = (float*)alloc((size_t)N * 4);

    hipLaunchKernelGGL(k_zero,     dim3((N + 255) / 256),  dim3(256),  0, stream, deg, N);
    hipLaunchKernelGGL(k_hist,     dim3((ET + 255) / 256), dim3(256),  0, stream, ei, E, ET, deg);
    hipLaunchKernelGGL(k_scan_blk, dim3(nScanBlk),         dim3(256),  0, stream, deg, N, rowptr, bsum);
    hipLaunchKernelGGL(k_scan_top, dim3(1),                dim3(64),   0, stream, bsum, nScanBlk);
    hipLaunchKernelGGL(k_scan_add, dim3(nScanBlk),         dim3(256),  0, stream, bsum, N, ET, rowptr, cursor);
    hipLaunchKernelGGL(k_scatter,  dim3((ET + 255) / 256), dim3(256),  0, stream, ei, E, ET, cursor, csr_src);
    hipLaunchKernelGGL(k_gemm1,    dim3(N / 16),  dim3(512), 0, stream, x, W1, a_src1, a_dst1, h1, asrc1, adst1, N);
    hipLaunchKernelGGL(k_agg1,     dim3(N),       dim3(128), 0, stream, rowptr, csr_src, h1, asrc1, adst1, b1, x2);
    hipLaunchKernelGGL(k_gemm2,    dim3((N + 31) / 32), dim3(256), 0, stream, x2, W2, a_src2, a_dst2, h2, asrc2, adst2, N);
    hipLaunchKernelGGL(k_agg2,     dim3(N / 4),   dim3(128), 0, stream, rowptr, csr_src, h2, asrc2, adst2, b2, out);
}

// Round 3
// 495.149 us; speedup vs baseline: 1.7036x; 1.0472x over previous
//
#include <hip/hip_runtime.h>
#include <math.h>

#define NEG_SLOPE 0.2f
#define EPSV 1e-16f
#define NPART 8

// ---------------- CSR build (atomic-free scatter via partitioned rank) ----------------

// 8-way partitioned histogram; records each edge's rank within (partition,dst).
__global__ void k_hist_rank(const int* __restrict__ ei, int E, int ET, int N,
                            int* __restrict__ degp, int* __restrict__ rank){
    int i = blockIdx.x * 256 + threadIdx.x;
    if (i < ET){
        int d = (i < E) ? ei[E + i] : (i - E);   // self loops appended
        int p = blockIdx.x & (NPART - 1);
        rank[i] = atomicAdd(&degp[p * N + d], 1);
    }
}

// per-node: total degree + exclusive prefix over partitions
__global__ void k_combine(const int* __restrict__ degp, int N,
                          int* __restrict__ deg, int* __restrict__ poff){
    int n = blockIdx.x * 256 + threadIdx.x;
    if (n < N){
        int s = 0;
        #pragma unroll
        for (int p = 0; p < NPART; p++){
            int t = degp[p * N + n];
            poff[p * N + n] = s;
            s += t;
        }
        deg[n] = s;
    }
}

// hierarchical scan: 49 blocks x 1024 elems -> top scan of 49 -> fixup
__global__ void k_scan_blk(const int* __restrict__ deg, int N,
                           int* __restrict__ rowptr, int* __restrict__ bsum){
    int b = blockIdx.x, t = threadIdx.x;
    int base = b * 1024 + t * 4;
    int v[4];
    #pragma unroll
    for (int j = 0; j < 4; j++) v[j] = (base + j < N) ? deg[base + j] : 0;
    int s = v[0] + v[1] + v[2] + v[3];
    int lane = t & 63, wid = t >> 6;
    int x = s;
    #pragma unroll
    for (int off = 1; off < 64; off <<= 1){
        int y = __shfl_up(x, off, 64);
        if (lane >= off) x += y;
    }
    __shared__ int ws[4];
    if (lane == 63) ws[wid] = x;
    __syncthreads();
    int woff = 0;
    for (int w = 0; w < wid; w++) woff += ws[w];
    int run = woff + x - s;
    #pragma unroll
    for (int j = 0; j < 4; j++){
        if (base + j < N) rowptr[base + j] = run;
        run += v[j];
    }
    if (t == 255) bsum[b] = woff + x;
}

__global__ void k_scan_top(int* bsum, int nb){
    int t = threadIdx.x;
    int v = (t < nb) ? bsum[t] : 0;
    int x = v;
    #pragma unroll
    for (int off = 1; off < 64; off <<= 1){
        int y = __shfl_up(x, off, 64);
        if (t >= off) x += y;
    }
    if (t < nb) bsum[t] = x - v;   // exclusive
}

__global__ void k_scan_add(const int* __restrict__ bsum, int N, int ET,
                           int* __restrict__ rowptr){
    int b = blockIdx.x, t = threadIdx.x;
    int off = bsum[b];
    int base = b * 1024 + t * 4;
    #pragma unroll
    for (int j = 0; j < 4; j++)
        if (base + j < N) rowptr[base + j] += off;
    if (b == 0 && t == 0) rowptr[N] = ET;
}

// poff[p][n] += rowptr[n]  (grid.y = partition)
__global__ void k_poff_add(const int* __restrict__ rowptr, int N, int* __restrict__ poff){
    int n = blockIdx.x * 256 + threadIdx.x;
    if (n < N) poff[blockIdx.y * N + n] += rowptr[n];
}

// atomic-free scatter; also precomputes per-edge softmax numerators (4 heads)
__launch_bounds__(256)
__global__ void k_scatter2(const int* __restrict__ ei, int E, int ET, int N,
                           const int* __restrict__ poff, const int* __restrict__ rank,
                           const float* __restrict__ asrc1, const float* __restrict__ adst1,
                           int* __restrict__ csr_src, int* __restrict__ csr_dst,
                           float* __restrict__ ew1){
    int i = blockIdx.x * 256 + threadIdx.x;
    if (i >= ET) return;
    int s, d;
    if (i < E){ s = ei[i]; d = ei[E + i]; } else { s = i - E; d = s; }
    int p = blockIdx.x & (NPART - 1);
    int pos = poff[p * N + d] + rank[i];
    csr_src[pos] = s;
    csr_dst[pos] = d;
    float4 as = *(const float4*)&asrc1[s << 2];
    float4 ad = *(const float4*)&adst1[d << 2];
    float4 w;
    float e;
    e = as.x + ad.x; e = fmaxf(e, NEG_SLOPE * e); w.x = __expf(e);
    e = as.y + ad.y; e = fmaxf(e, NEG_SLOPE * e); w.y = __expf(e);
    e = as.z + ad.z; e = fmaxf(e, NEG_SLOPE * e); w.z = __expf(e);
    e = as.w + ad.w; e = fmaxf(e, NEG_SLOPE * e); w.w = __expf(e);
    *(float4*)&ew1[(size_t)pos << 2] = w;
}

// ---------------- GEMM1: h1 = x @ W1, fused alpha epilogue ----------------

__launch_bounds__(512)
__global__ void k_gemm1(const float* __restrict__ x, const float* __restrict__ W1,
                        const float* __restrict__ a_src, const float* __restrict__ a_dst,
                        float* __restrict__ h1, float* __restrict__ asrc1,
                        float* __restrict__ adst1, int N){
    __shared__ float Wl[128 * 128];   // [k][col]
    __shared__ float xl[16][128];
    int t = threadIdx.x;
    int cg = t & 31, ns = t >> 5;
    for (int idx = t; idx < 128 * 128 / 4; idx += 512)
        *(float4*)&Wl[idx * 4] = *(const float4*)&W1[idx * 4];
    float4 a4s = *(const float4*)&a_src[cg * 4];
    float4 a4d = *(const float4*)&a_dst[cg * 4];
    int n0 = blockIdx.x * 16;
    *(float4*)&xl[ns][cg * 4] = *(const float4*)&x[(size_t)(n0 + ns) * 128 + cg * 4];
    __syncthreads();
    float4 acc = {0.f, 0.f, 0.f, 0.f};
    #pragma unroll 8
    for (int k = 0; k < 128; k++){
        float xs = xl[ns][k];
        float4 w = *(float4*)&Wl[k * 128 + cg * 4];
        acc.x = fmaf(xs, w.x, acc.x);
        acc.y = fmaf(xs, w.y, acc.y);
        acc.z = fmaf(xs, w.z, acc.z);
        acc.w = fmaf(xs, w.w, acc.w);
    }
    int n = n0 + ns;
    *(float4*)&h1[(size_t)n * 128 + cg * 4] = acc;
    float vs = acc.x * a4s.x + acc.y * a4s.y + acc.z * a4s.z + acc.w * a4s.w;
    float vd = acc.x * a4d.x + acc.y * a4d.y + acc.z * a4d.z + acc.w * a4d.w;
    #pragma unroll
    for (int m = 1; m <= 4; m <<= 1){
        vs += __shfl_xor(vs, m, 64);
        vd += __shfl_xor(vd, m, 64);
    }
    if ((cg & 7) == 0){
        int head = cg >> 3;
        asrc1[n * 4 + head] = vs;
        adst1[n * 4 + head] = vd;
    }
}

// ---------------- Aggregation layer 1: pure gather+FMA, weights precomputed ----------------

__launch_bounds__(128)
__global__ void k_agg1(const int* __restrict__ rowptr, const int* __restrict__ csr_src,
                       const float* __restrict__ ew1, const float* __restrict__ h1,
                       const float* __restrict__ b1, float* __restrict__ x2){
    int n = blockIdx.x;
    int t = threadIdx.x;
    int hh = t >> 5;
    int start = rowptr[n], end = rowptr[n + 1];
    float ssum = 0.f, acc = 0.f;
    int i = start;
    for (; i + 2 <= end; i += 2){
        int s0 = csr_src[i], s1 = csr_src[i + 1];
        float w0 = ew1[(i << 2) + hh];
        float w1 = ew1[((i + 1) << 2) + hh];
        float g0 = h1[(s0 << 7) + t];
        float g1 = h1[(s1 << 7) + t];
        ssum += w0 + w1;
        acc = fmaf(w0, g0, acc);
        acc = fmaf(w1, g1, acc);
    }
    if (i < end){
        int s0 = csr_src[i];
        float w0 = ew1[(i << 2) + hh];
        ssum += w0;
        acc = fmaf(w0, h1[(s0 << 7) + t], acc);
    }
    float o = acc / (ssum + EPSV) + b1[t];
    x2[((size_t)n << 7) + t] = (o > 0.f) ? o : expm1f(o);   // ELU fused
}

// ---------------- GEMM2: h2 = x2 @ W2, fused alpha2 epilogue ----------------

__launch_bounds__(256)
__global__ void k_gemm2(const float* __restrict__ x2, const float* __restrict__ W2,
                        const float* __restrict__ a_src, const float* __restrict__ a_dst,
                        float* __restrict__ h2, float* __restrict__ asrc2,
                        float* __restrict__ adst2, int N){
    __shared__ float Wl[128 * 32];
    __shared__ float xl[32][132];
    int t = threadIdx.x;
    int cg = t & 7, ns = t >> 3;
    for (int idx = t; idx < 1024; idx += 256)
        *(float4*)&Wl[idx * 4] = *(const float4*)&W2[idx * 4];
    int n0 = blockIdx.x * 32;
    for (int idx = t; idx < 1024; idx += 256){
        int nn = idx >> 5, k4 = idx & 31;
        int nn_g = n0 + nn;
        float4 v = {0.f, 0.f, 0.f, 0.f};
        if (nn_g < N) v = *(const float4*)&x2[(size_t)nn_g * 128 + k4 * 4];
        *(float4*)&xl[nn][k4 * 4] = v;
    }
    __syncthreads();
    float4 acc = {0.f, 0.f, 0.f, 0.f};
    #pragma unroll 8
    for (int k = 0; k < 128; k++){
        float xs = xl[ns][k];
        float4 w = *(float4*)&Wl[k * 32 + cg * 4];
        acc.x = fmaf(xs, w.x, acc.x);
        acc.y = fmaf(xs, w.y, acc.y);
        acc.z = fmaf(xs, w.z, acc.z);
        acc.w = fmaf(xs, w.w, acc.w);
    }
    int n = n0 + ns;
    if (n < N){
        *(float4*)&h2[(size_t)n * 32 + cg * 4] = acc;
        float4 a4s = *(const float4*)&a_src[cg * 4];
        float4 a4d = *(const float4*)&a_dst[cg * 4];
        float vs = acc.x * a4s.x + acc.y * a4s.y + acc.z * a4s.z + acc.w * a4s.w;
        float vd = acc.x * a4d.x + acc.y * a4d.y + acc.z * a4d.z + acc.w * a4d.w;
        #pragma unroll
        for (int m = 1; m <= 4; m <<= 1){
            vs += __shfl_xor(vs, m, 64);
            vd += __shfl_xor(vd, m, 64);
        }
        if (cg == 0){ asrc2[n] = vs; adst2[n] = vd; }
    }
}

// per-edge layer-2 weights (streaming)
__global__ void k_ew2(const int* __restrict__ csr_src, const int* __restrict__ csr_dst,
                      const float* __restrict__ asrc2, const float* __restrict__ adst2,
                      int ET, float* __restrict__ ew2){
    int i = blockIdx.x * 256 + threadIdx.x;
    if (i < ET){
        float e = asrc2[csr_src[i]] + adst2[csr_dst[i]];
        e = fmaxf(e, NEG_SLOPE * e);
        ew2[i] = __expf(e);
    }
}

// ---------------- Aggregation layer 2: 4 nodes per 128-thr block ----------------

__launch_bounds__(128)
__global__ void k_agg2(const int* __restrict__ rowptr, const int* __restrict__ csr_src,
                       const float* __restrict__ ew2, const float* __restrict__ h2,
                       const float* __restrict__ b2, float* __restrict__ out){
    int t = threadIdx.x;
    int n = blockIdx.x * 4 + (t >> 5);
    int c = t & 31;
    int start = rowptr[n], end = rowptr[n + 1];
    float ssum = 0.f, acc = 0.f;
    int i = start;
    for (; i + 2 <= end; i += 2){
        int s0 = csr_src[i], s1 = csr_src[i + 1];
        float w0 = ew2[i], w1 = ew2[i + 1];
        float g0 = h2[(s0 << 5) + c];
        float g1 = h2[(s1 << 5) + c];
        ssum += w0 + w1;
        acc = fmaf(w0, g0, acc);
        acc = fmaf(w1, g1, acc);
    }
    if (i < end){
        int s0 = csr_src[i];
        float w0 = ew2[i];
        ssum += w0;
        acc = fmaf(w0, h2[(s0 << 5) + c], acc);
    }
    out[((size_t)n << 5) + c] = acc / (ssum + EPSV) + b2[c];
}

// ---------------- launch ----------------

extern "C" void kernel_launch(void* const* d_in, const int* in_sizes, int n_in,
                              void* d_out, int out_size, void* d_ws, size_t ws_size,
                              hipStream_t stream){
    const float* x      = (const float*)d_in[0];
    const int*   ei     = (const int*)  d_in[1];
    const float* W1     = (const float*)d_in[2];
    const float* a_src1 = (const float*)d_in[3];
    const float* a_dst1 = (const float*)d_in[4];
    const float* b1     = (const float*)d_in[5];
    const float* W2     = (const float*)d_in[6];
    const float* a_src2 = (const float*)d_in[7];
    const float* a_dst2 = (const float*)d_in[8];
    const float* b2     = (const float*)d_in[9];
    float* out = (float*)d_out;

    int N  = in_sizes[0] / 128;
    int E  = in_sizes[1] / 2;
    int ET = E + N;
    int nScanBlk = (N + 1023) / 1024;
    int G  = (ET + 255) / 256;

    char* ws = (char*)d_ws;
    size_t off = 0;
    auto alloc = [&](size_t bytes) -> char* {
        char* p = ws + off;
        off += (bytes + 255) & ~(size_t)255;
        return p;
    };
    int*   degp    = (int*)  alloc((size_t)NPART * N * 4);
    int*   deg     = (int*)  alloc((size_t)N * 4);
    int*   rowptr  = (int*)  alloc((size_t)(N + 1) * 4);
    int*   bsum    = (int*)  alloc((size_t)nScanBlk * 4);
    int*   rank    = (int*)  alloc((size_t)ET * 4);
    int*   poff    = (int*)  alloc((size_t)NPART * N * 4);
    int*   csr_src = (int*)  alloc((size_t)ET * 4);
    int*   csr_dst = (int*)  alloc((size_t)ET * 4);
    float* ew1     = (float*)alloc((size_t)ET * 4 * 4);
    float* ew2     = (float*)alloc((size_t)ET * 4);
    float* h1      = (float*)alloc((size_t)N * 128 * 4);
    float* x2      = (float*)alloc((size_t)N * 128 * 4);
    float* asrc1   = (float*)alloc((size_t)N * 4 * 4);
    float* adst1   = (float*)alloc((size_t)N * 4 * 4);
    float* h2      = (float*)alloc((size_t)N * 32 * 4);
    float* asrc2   = (float*)alloc((size_t)N * 4);
    float* adst2   = (float*)alloc((size_t)N * 4);

    hipMemsetAsync(degp, 0, (size_t)NPART * N * 4, stream);
    hipLaunchKernelGGL(k_hist_rank, dim3(G), dim3(256), 0, stream, ei, E, ET, N, degp, rank);
    hipLaunchKernelGGL(k_combine,   dim3((N + 255) / 256), dim3(256), 0, stream, degp, N, deg, poff);
    hipLaunchKernelGGL(k_scan_blk,  dim3(nScanBlk), dim3(256), 0, stream, deg, N, rowptr, bsum);
    hipLaunchKernelGGL(k_scan_top,  dim3(1),        dim3(64),  0, stream, bsum, nScanBlk);
    hipLaunchKernelGGL(k_scan_add,  dim3(nScanBlk), dim3(256), 0, stream, bsum, N, ET, rowptr);
    hipLaunchKernelGGL(k_poff_add,  dim3((N + 255) / 256, NPART), dim3(256), 0, stream, rowptr, N, poff);
    hipLaunchKernelGGL(k_gemm1,     dim3(N / 16), dim3(512), 0, stream, x, W1, a_src1, a_dst1, h1, asrc1, adst1, N);
    hipLaunchKernelGGL(k_scatter2,  dim3(G), dim3(256), 0, stream, ei, E, ET, N, poff, rank,
                       asrc1, adst1, csr_src, csr_dst, ew1);
    hipLaunchKernelGGL(k_agg1,      dim3(N), dim3(128), 0, stream, rowptr, csr_src, ew1, h1, b1, x2);
    hipLaunchKernelGGL(k_gemm2,     dim3((N + 31) / 32), dim3(256), 0, stream, x2, W2, a_src2, a_dst2, h2, asrc2, adst2, N);
    hipLaunchKernelGGL(k_ew2,       dim3(G), dim3(256), 0, stream, csr_src, csr_dst, asrc2, adst2, ET, ew2);
    hipLaunchKernelGGL(k_agg2,      dim3(N / 4), dim3(128), 0, stream, rowptr, csr_src, ew2, h2, b2, out);
}

// Round 5
// 400.759 us; speedup vs baseline: 2.1048x; 1.2355x over previous
//
#include <hip/hip_runtime.h>
#include <math.h>

#define NEG_SLOPE 0.2f
#define EPSV 1e-16f
#define NPART 8

// ---------------- CSR build ----------------

// 8-way partitioned histogram; records each edge's rank within (partition,dst).
__global__ void k_hist_rank(const int* __restrict__ ei, int E, int ET, int N,
                            int* __restrict__ degp, int* __restrict__ rank){
    int i = blockIdx.x * 256 + threadIdx.x;
    if (i < ET){
        int d = (i < E) ? ei[E + i] : (i - E);   // self loops appended
        int p = blockIdx.x & (NPART - 1);
        rank[i] = atomicAdd(&degp[p * N + d], 1);
    }
}

// per-node: total degree + exclusive prefix over partitions
__global__ void k_combine(const int* __restrict__ degp, int N,
                          int* __restrict__ deg, int* __restrict__ poff){
    int n = blockIdx.x * 256 + threadIdx.x;
    if (n < N){
        int s = 0;
        #pragma unroll
        for (int p = 0; p < NPART; p++){
            int t = degp[p * N + n];
            poff[p * N + n] = s;
            s += t;
        }
        deg[n] = s;
    }
}

// hierarchical scan: blocks of 1024 elems -> top scan -> fixup
__global__ void k_scan_blk(const int* __restrict__ deg, int N,
                           int* __restrict__ rowptr, int* __restrict__ bsum){
    int b = blockIdx.x, t = threadIdx.x;
    int base = b * 1024 + t * 4;
    int v[4];
    #pragma unroll
    for (int j = 0; j < 4; j++) v[j] = (base + j < N) ? deg[base + j] : 0;
    int s = v[0] + v[1] + v[2] + v[3];
    int lane = t & 63, wid = t >> 6;
    int x = s;
    #pragma unroll
    for (int off = 1; off < 64; off <<= 1){
        int y = __shfl_up(x, off, 64);
        if (lane >= off) x += y;
    }
    __shared__ int ws[4];
    if (lane == 63) ws[wid] = x;
    __syncthreads();
    int woff = 0;
    for (int w = 0; w < wid; w++) woff += ws[w];
    int run = woff + x - s;
    #pragma unroll
    for (int j = 0; j < 4; j++){
        if (base + j < N) rowptr[base + j] = run;
        run += v[j];
    }
    if (t == 255) bsum[b] = woff + x;
}

__global__ void k_scan_top(int* bsum, int nb){
    int t = threadIdx.x;
    int v = (t < nb) ? bsum[t] : 0;
    int x = v;
    #pragma unroll
    for (int off = 1; off < 64; off <<= 1){
        int y = __shfl_up(x, off, 64);
        if (t >= off) x += y;
    }
    if (t < nb) bsum[t] = x - v;   // exclusive
}

// rowptr += block offset; poff[p][n] += final rowptr[n]
__global__ void k_finalize(const int* __restrict__ bsum, int N, int ET,
                           int* __restrict__ rowptr, int* __restrict__ poff){
    int n = blockIdx.x * 256 + threadIdx.x;
    if (n < N){
        int r = rowptr[n] + bsum[n >> 10];
        rowptr[n] = r;
        #pragma unroll
        for (int p = 0; p < NPART; p++) poff[p * N + n] += r;
    }
    if (n == 0) rowptr[N] = ET;
}

// atomic-free scatter (src only; dst implicit via rowptr ranges)
__launch_bounds__(256)
__global__ void k_scatter2(const int* __restrict__ ei, int E, int ET, int N,
                           const int* __restrict__ poff, const int* __restrict__ rank,
                           int* __restrict__ csr_src){
    int i = blockIdx.x * 256 + threadIdx.x;
    if (i >= ET) return;
    int s, d;
    if (i < E){ s = ei[i]; d = ei[E + i]; } else { s = i - E; d = s; }
    int p = blockIdx.x & (NPART - 1);
    csr_src[poff[p * N + d] + rank[i]] = s;
}

// ---------------- GEMM1: h1 = x @ W1, 4-node register blocking ----------------

__launch_bounds__(256)
__global__ void k_gemm1(const float* __restrict__ x, const float* __restrict__ W1,
                        const float* __restrict__ a_src, const float* __restrict__ a_dst,
                        float* __restrict__ h1, float* __restrict__ asrc1,
                        float* __restrict__ adst1, int N){
    __shared__ float Wl[128 * 128];   // 64 KB, [k][col]
    __shared__ float xl[32 * 128];    // 16 KB
    int t = threadIdx.x;
    int cg = t & 31, ns = t >> 5;     // ns in 0..7
    for (int idx = t; idx < 4096; idx += 256)
        *(float4*)&Wl[idx * 4] = *(const float4*)&W1[idx * 4];
    int n0 = blockIdx.x * 32;
    for (int idx = t; idx < 1024; idx += 256){
        int row = idx >> 5, k4 = idx & 31;
        float4 v = {0.f, 0.f, 0.f, 0.f};
        if (n0 + row < N) v = *(const float4*)&x[(size_t)(n0 + row) * 128 + k4 * 4];
        *(float4*)&xl[row * 128 + k4 * 4] = v;
    }
    __syncthreads();
    float4 acc0 = {0,0,0,0}, acc1 = {0,0,0,0}, acc2 = {0,0,0,0}, acc3 = {0,0,0,0};
    #pragma unroll 4
    for (int k = 0; k < 128; k++){
        float4 w = *(float4*)&Wl[k * 128 + cg * 4];
        float x0 = xl[(ns     ) * 128 + k];
        float x1 = xl[(ns +  8) * 128 + k];
        float x2v= xl[(ns + 16) * 128 + k];
        float x3 = xl[(ns + 24) * 128 + k];
        acc0.x = fmaf(x0, w.x, acc0.x); acc0.y = fmaf(x0, w.y, acc0.y);
        acc0.z = fmaf(x0, w.z, acc0.z); acc0.w = fmaf(x0, w.w, acc0.w);
        acc1.x = fmaf(x1, w.x, acc1.x); acc1.y = fmaf(x1, w.y, acc1.y);
        acc1.z = fmaf(x1, w.z, acc1.z); acc1.w = fmaf(x1, w.w, acc1.w);
        acc2.x = fmaf(x2v, w.x, acc2.x); acc2.y = fmaf(x2v, w.y, acc2.y);
        acc2.z = fmaf(x2v, w.z, acc2.z); acc2.w = fmaf(x2v, w.w, acc2.w);
        acc3.x = fmaf(x3, w.x, acc3.x); acc3.y = fmaf(x3, w.y, acc3.y);
        acc3.z = fmaf(x3, w.z, acc3.z); acc3.w = fmaf(x3, w.w, acc3.w);
    }
    float4 a4s = *(const float4*)&a_src[cg * 4];
    float4 a4d = *(const float4*)&a_dst[cg * 4];
    float4 accs[4] = {acc0, acc1, acc2, acc3};
    #pragma unroll
    for (int j = 0; j < 4; j++){
        int n = n0 + ns + 8 * j;
        if (n >= N) continue;
        float4 a = accs[j];
        *(float4*)&h1[(size_t)n * 128 + cg * 4] = a;
        float vs = a.x * a4s.x + a.y * a4s.y + a.z * a4s.z + a.w * a4s.w;
        float vd = a.x * a4d.x + a.y * a4d.y + a.z * a4d.z + a.w * a4d.w;
        #pragma unroll
        for (int m = 1; m <= 4; m <<= 1){
            vs += __shfl_xor(vs, m, 64);
            vd += __shfl_xor(vd, m, 64);
        }
        if ((cg & 7) == 0){
            int head = cg >> 3;
            asrc1[n * 4 + head] = vs;
            adst1[n * 4 + head] = vd;
        }
    }
}

// ---------------- Aggregation L1: 8 groups x 32 lanes, float4 gather ----------------
// lane l covers columns 4l..4l+3, all in head l>>3; denominator is PER HEAD.

__launch_bounds__(256)
__global__ void k_agg1(const int* __restrict__ rowptr, const int* __restrict__ csr_src,
                       const float* __restrict__ asrc1, const float* __restrict__ adst1,
                       const float* __restrict__ h1,
                       const float* __restrict__ b1, float* __restrict__ x2){
    int n = blockIdx.x;
    int t = threadIdx.x;
    int g = t >> 5, l = t & 31, head = l >> 3;
    int start = rowptr[n], end = rowptr[n + 1];
    float adn = adst1[(n << 2) + head];
    float4 acc = {0.f, 0.f, 0.f, 0.f};
    float ssum = 0.f;
    for (int i = start + g; i < end; i += 8){
        int s = csr_src[i];
        float e = asrc1[(s << 2) + head] + adn;
        e = fmaxf(e, NEG_SLOPE * e);
        float w = __expf(e);
        float4 gv = *(const float4*)&h1[((size_t)s << 7) + l * 4];
        ssum += w;
        acc.x = fmaf(w, gv.x, acc.x); acc.y = fmaf(w, gv.y, acc.y);
        acc.z = fmaf(w, gv.z, acc.z); acc.w = fmaf(w, gv.w, acc.w);
    }
    __shared__ float racc[8][128];
    __shared__ float rs[8][4];          // per-(group, head) denominators
    *(float4*)&racc[g][l * 4] = acc;
    if ((l & 7) == 0) rs[g][head] = ssum;
    __syncthreads();
    if (t < 128){
        int h = t >> 5;                 // head of output column t
        float a = 0.f;
        #pragma unroll
        for (int p = 0; p < 8; p++) a += racc[p][t];
        float S = 0.f;
        #pragma unroll
        for (int p = 0; p < 8; p++) S += rs[p][h];
        float o = a / (S + EPSV) + b1[t];
        x2[((size_t)n << 7) + t] = (o > 0.f) ? o : expm1f(o);   // ELU fused
    }
}

// ---------------- GEMM2: h2 = x2 @ W2, 4-node blocking ----------------

__launch_bounds__(256)
__global__ void k_gemm2(const float* __restrict__ x2, const float* __restrict__ W2,
                        const float* __restrict__ a_src, const float* __restrict__ a_dst,
                        float* __restrict__ h2, float* __restrict__ asrc2,
                        float* __restrict__ adst2, int N){
    __shared__ float Wl[128 * 32];    // 16 KB
    __shared__ float xl[128 * 128];   // 64 KB
    int t = threadIdx.x;
    int cg = t & 7, ns = t >> 3;      // ns in 0..31
    for (int idx = t; idx < 1024; idx += 256)
        *(float4*)&Wl[idx * 4] = *(const float4*)&W2[idx * 4];
    int n0 = blockIdx.x * 128;
    for (int idx = t; idx < 4096; idx += 256){
        int row = idx >> 5, k4 = idx & 31;
        float4 v = {0.f, 0.f, 0.f, 0.f};
        if (n0 + row < N) v = *(const float4*)&x2[(size_t)(n0 + row) * 128 + k4 * 4];
        *(float4*)&xl[row * 128 + k4 * 4] = v;
    }
    __syncthreads();
    float4 acc0 = {0,0,0,0}, acc1 = {0,0,0,0}, acc2 = {0,0,0,0}, acc3 = {0,0,0,0};
    #pragma unroll 4
    for (int k = 0; k < 128; k++){
        float4 w = *(float4*)&Wl[k * 32 + cg * 4];
        float x0 = xl[(ns      ) * 128 + k];
        float x1 = xl[(ns +  32) * 128 + k];
        float x2v= xl[(ns +  64) * 128 + k];
        float x3 = xl[(ns +  96) * 128 + k];
        acc0.x = fmaf(x0, w.x, acc0.x); acc0.y = fmaf(x0, w.y, acc0.y);
        acc0.z = fmaf(x0, w.z, acc0.z); acc0.w = fmaf(x0, w.w, acc0.w);
        acc1.x = fmaf(x1, w.x, acc1.x); acc1.y = fmaf(x1, w.y, acc1.y);
        acc1.z = fmaf(x1, w.z, acc1.z); acc1.w = fmaf(x1, w.w, acc1.w);
        acc2.x = fmaf(x2v, w.x, acc2.x); acc2.y = fmaf(x2v, w.y, acc2.y);
        acc2.z = fmaf(x2v, w.z, acc2.z); acc2.w = fmaf(x2v, w.w, acc2.w);
        acc3.x = fmaf(x3, w.x, acc3.x); acc3.y = fmaf(x3, w.y, acc3.y);
        acc3.z = fmaf(x3, w.z, acc3.z); acc3.w = fmaf(x3, w.w, acc3.w);
    }
    float4 a4s = *(const float4*)&a_src[cg * 4];
    float4 a4d = *(const float4*)&a_dst[cg * 4];
    float4 accs[4] = {acc0, acc1, acc2, acc3};
    #pragma unroll
    for (int j = 0; j < 4; j++){
        int n = n0 + ns + 32 * j;
        if (n >= N) continue;
        float4 a = accs[j];
        *(float4*)&h2[(size_t)n * 32 + cg * 4] = a;
        float vs = a.x * a4s.x + a.y * a4s.y + a.z * a4s.z + a.w * a4s.w;
        float vd = a.x * a4d.x + a.y * a4d.y + a.z * a4d.z + a.w * a4d.w;
        #pragma unroll
        for (int m = 1; m <= 4; m <<= 1){
            vs += __shfl_xor(vs, m, 64);
            vd += __shfl_xor(vd, m, 64);
        }
        if (cg == 0){ asrc2[n] = vs; adst2[n] = vd; }
    }
}

// ---------------- Aggregation L2: wave per node, 8 groups x 8 lanes ----------------

__launch_bounds__(256)
__global__ void k_agg2(const int* __restrict__ rowptr, const int* __restrict__ csr_src,
                       const float* __restrict__ asrc2, const float* __restrict__ adst2,
                       const float* __restrict__ h2,
                       const float* __restrict__ b2, float* __restrict__ out){
    int t = threadIdx.x;
    int n = blockIdx.x * 4 + (t >> 6);
    int lane = t & 63, g = lane >> 3, l = lane & 7;
    int start = rowptr[n], end = rowptr[n + 1];
    float adn = adst2[n];
    float4 acc = {0.f, 0.f, 0.f, 0.f};
    float ssum = 0.f;
    for (int i = start + g; i < end; i += 8){
        int s = csr_src[i];
        float e = asrc2[s] + adn;
        e = fmaxf(e, NEG_SLOPE * e);
        float w = __expf(e);
        float4 gv = *(const float4*)&h2[((size_t)s << 5) + l * 4];
        ssum += w;
        acc.x = fmaf(w, gv.x, acc.x); acc.y = fmaf(w, gv.y, acc.y);
        acc.z = fmaf(w, gv.z, acc.z); acc.w = fmaf(w, gv.w, acc.w);
    }
    #pragma unroll
    for (int m = 8; m <= 32; m <<= 1){
        acc.x += __shfl_xor(acc.x, m, 64);
        acc.y += __shfl_xor(acc.y, m, 64);
        acc.z += __shfl_xor(acc.z, m, 64);
        acc.w += __shfl_xor(acc.w, m, 64);
        ssum  += __shfl_xor(ssum,  m, 64);
    }
    if (g == 0){
        float inv = 1.f / (ssum + EPSV);
        const float4 b4 = *(const float4*)&b2[l * 4];
        float4 o;
        o.x = acc.x * inv + b4.x; o.y = acc.y * inv + b4.y;
        o.z = acc.z * inv + b4.z; o.w = acc.w * inv + b4.w;
        *(float4*)&out[((size_t)n << 5) + l * 4] = o;
    }
}

// ---------------- launch ----------------

extern "C" void kernel_launch(void* const* d_in, const int* in_sizes, int n_in,
                              void* d_out, int out_size, void* d_ws, size_t ws_size,
                              hipStream_t stream){
    const float* x      = (const float*)d_in[0];
    const int*   ei     = (const int*)  d_in[1];
    const float* W1     = (const float*)d_in[2];
    const float* a_src1 = (const float*)d_in[3];
    const float* a_dst1 = (const float*)d_in[4];
    const float* b1     = (const float*)d_in[5];
    const float* W2     = (const float*)d_in[6];
    const float* a_src2 = (const float*)d_in[7];
    const float* a_dst2 = (const float*)d_in[8];
    const float* b2     = (const float*)d_in[9];
    float* out = (float*)d_out;

    int N  = in_sizes[0] / 128;
    int E  = in_sizes[1] / 2;
    int ET = E + N;
    int nScanBlk = (N + 1023) / 1024;
    int G  = (ET + 255) / 256;

    char* ws = (char*)d_ws;
    size_t off = 0;
    auto alloc = [&](size_t bytes) -> char* {
        char* p = ws + off;
        off += (bytes + 255) & ~(size_t)255;
        return p;
    };
    int*   degp    = (int*)  alloc((size_t)NPART * N * 4);
    int*   deg     = (int*)  alloc((size_t)N * 4);
    int*   rowptr  = (int*)  alloc((size_t)(N + 1) * 4);
    int*   bsum    = (int*)  alloc((size_t)nScanBlk * 4);
    int*   rank    = (int*)  alloc((size_t)ET * 4);
    int*   poff    = (int*)  alloc((size_t)NPART * N * 4);
    int*   csr_src = (int*)  alloc((size_t)ET * 4);
    float* h1      = (float*)alloc((size_t)N * 128 * 4);
    float* x2      = (float*)alloc((size_t)N * 128 * 4);
    float* asrc1   = (float*)alloc((size_t)N * 4 * 4);
    float* adst1   = (float*)alloc((size_t)N * 4 * 4);
    float* h2      = (float*)alloc((size_t)N * 32 * 4);
    float* asrc2   = (float*)alloc((size_t)N * 4);
    float* adst2   = (float*)alloc((size_t)N * 4);

    hipMemsetAsync(degp, 0, (size_t)NPART * N * 4, stream);
    hipLaunchKernelGGL(k_hist_rank, dim3(G), dim3(256), 0, stream, ei, E, ET, N, degp, rank);
    hipLaunchKernelGGL(k_combine,   dim3((N + 255) / 256), dim3(256), 0, stream, degp, N, deg, poff);
    hipLaunchKernelGGL(k_scan_blk,  dim3(nScanBlk), dim3(256), 0, stream, deg, N, rowptr, bsum);
    hipLaunchKernelGGL(k_scan_top,  dim3(1),        dim3(64),  0, stream, bsum, nScanBlk);
    hipLaunchKernelGGL(k_finalize,  dim3((N + 255) / 256), dim3(256), 0, stream, bsum, N, ET, rowptr, poff);
    hipLaunchKernelGGL(k_scatter2,  dim3(G), dim3(256), 0, stream, ei, E, ET, N, poff, rank, csr_src);
    hipLaunchKernelGGL(k_gemm1,     dim3((N + 31) / 32), dim3(256), 0, stream, x, W1, a_src1, a_dst1, h1, asrc1, adst1, N);
    hipLaunchKernelGGL(k_agg1,      dim3(N), dim3(256), 0, stream, rowptr, csr_src, asrc1, adst1, h1, b1, x2);
    hipLaunchKernelGGL(k_gemm2,     dim3((N + 127) / 128), dim3(256), 0, stream, x2, W2, a_src2, a_dst2, h2, asrc2, adst2, N);
    hipLaunchKernelGGL(k_agg2,      dim3(N / 4), dim3(256), 0, stream, rowptr, csr_src, asrc2, adst2, h2, b2, out);
}

// Round 6
// 384.371 us; speedup vs baseline: 2.1946x; 1.0426x over previous
//
#include <hip/hip_runtime.h>
#include <math.h>

#define NEG_SLOPE 0.2f
#define EPSV 1e-16f
#define NPART 16

typedef _Float16 half4 __attribute__((ext_vector_type(4)));

// ---------------- CSR build ----------------

// 16-way partitioned histogram; records each edge's rank within (partition,dst).
__global__ void k_hist_rank(const int* __restrict__ ei, int E, int ET, int N,
                            int* __restrict__ degp, int* __restrict__ rank){
    int i = blockIdx.x * 256 + threadIdx.x;
    if (i < ET){
        int d = (i < E) ? ei[E + i] : (i - E);   // self loops appended
        int p = blockIdx.x & (NPART - 1);
        rank[i] = atomicAdd(&degp[p * N + d], 1);
    }
}

// per-node: total degree + exclusive prefix over partitions
__global__ void k_combine(const int* __restrict__ degp, int N,
                          int* __restrict__ deg, int* __restrict__ poff){
    int n = blockIdx.x * 256 + threadIdx.x;
    if (n < N){
        int s = 0;
        #pragma unroll
        for (int p = 0; p < NPART; p++){
            int t = degp[p * N + n];
            poff[p * N + n] = s;
            s += t;
        }
        deg[n] = s;
    }
}

// hierarchical scan: blocks of 1024 elems -> top scan -> fixup
__global__ void k_scan_blk(const int* __restrict__ deg, int N,
                           int* __restrict__ rowptr, int* __restrict__ bsum){
    int b = blockIdx.x, t = threadIdx.x;
    int base = b * 1024 + t * 4;
    int v[4];
    #pragma unroll
    for (int j = 0; j < 4; j++) v[j] = (base + j < N) ? deg[base + j] : 0;
    int s = v[0] + v[1] + v[2] + v[3];
    int lane = t & 63, wid = t >> 6;
    int x = s;
    #pragma unroll
    for (int off = 1; off < 64; off <<= 1){
        int y = __shfl_up(x, off, 64);
        if (lane >= off) x += y;
    }
    __shared__ int ws[4];
    if (lane == 63) ws[wid] = x;
    __syncthreads();
    int woff = 0;
    for (int w = 0; w < wid; w++) woff += ws[w];
    int run = woff + x - s;
    #pragma unroll
    for (int j = 0; j < 4; j++){
        if (base + j < N) rowptr[base + j] = run;
        run += v[j];
    }
    if (t == 255) bsum[b] = woff + x;
}

__global__ void k_scan_top(int* bsum, int nb){
    int t = threadIdx.x;
    int v = (t < nb) ? bsum[t] : 0;
    int x = v;
    #pragma unroll
    for (int off = 1; off < 64; off <<= 1){
        int y = __shfl_up(x, off, 64);
        if (t >= off) x += y;
    }
    if (t < nb) bsum[t] = x - v;   // exclusive
}

// rowptr += block offset; poff[p][n] += final rowptr[n]
__global__ void k_finalize(const int* __restrict__ bsum, int N, int ET,
                           int* __restrict__ rowptr, int* __restrict__ poff){
    int n = blockIdx.x * 256 + threadIdx.x;
    if (n < N){
        int r = rowptr[n] + bsum[n >> 10];
        rowptr[n] = r;
        #pragma unroll
        for (int p = 0; p < NPART; p++) poff[p * N + n] += r;
    }
    if (n == 0) rowptr[N] = ET;
}

// atomic-free scatter (src only; dst implicit via rowptr ranges)
__launch_bounds__(256)
__global__ void k_scatter2(const int* __restrict__ ei, int E, int ET, int N,
                           const int* __restrict__ poff, const int* __restrict__ rank,
                           int* __restrict__ csr_src){
    int i = blockIdx.x * 256 + threadIdx.x;
    if (i >= ET) return;
    int s, d;
    if (i < E){ s = ei[i]; d = ei[E + i]; } else { s = i - E; d = s; }
    int p = blockIdx.x & (NPART - 1);
    csr_src[poff[p * N + d] + rank[i]] = s;
}

// ---------------- GEMM1: h1 = x @ W1 (h1 stored fp16), 4-node register blocking ----

__launch_bounds__(256)
__global__ void k_gemm1(const float* __restrict__ x, const float* __restrict__ W1,
                        const float* __restrict__ a_src, const float* __restrict__ a_dst,
                        _Float16* __restrict__ h1h, float* __restrict__ asrc1,
                        float* __restrict__ adst1, int N){
    __shared__ float Wl[128 * 128];   // 64 KB, [k][col]
    __shared__ float xl[32 * 128];    // 16 KB
    int t = threadIdx.x;
    int cg = t & 31, ns = t >> 5;     // ns in 0..7
    for (int idx = t; idx < 4096; idx += 256)
        *(float4*)&Wl[idx * 4] = *(const float4*)&W1[idx * 4];
    int n0 = blockIdx.x * 32;
    for (int idx = t; idx < 1024; idx += 256){
        int row = idx >> 5, k4 = idx & 31;
        float4 v = {0.f, 0.f, 0.f, 0.f};
        if (n0 + row < N) v = *(const float4*)&x[(size_t)(n0 + row) * 128 + k4 * 4];
        *(float4*)&xl[row * 128 + k4 * 4] = v;
    }
    __syncthreads();
    float4 acc0 = {0,0,0,0}, acc1 = {0,0,0,0}, acc2 = {0,0,0,0}, acc3 = {0,0,0,0};
    #pragma unroll 4
    for (int k = 0; k < 128; k++){
        float4 w = *(float4*)&Wl[k * 128 + cg * 4];
        float x0 = xl[(ns     ) * 128 + k];
        float x1 = xl[(ns +  8) * 128 + k];
        float x2v= xl[(ns + 16) * 128 + k];
        float x3 = xl[(ns + 24) * 128 + k];
        acc0.x = fmaf(x0, w.x, acc0.x); acc0.y = fmaf(x0, w.y, acc0.y);
        acc0.z = fmaf(x0, w.z, acc0.z); acc0.w = fmaf(x0, w.w, acc0.w);
        acc1.x = fmaf(x1, w.x, acc1.x); acc1.y = fmaf(x1, w.y, acc1.y);
        acc1.z = fmaf(x1, w.z, acc1.z); acc1.w = fmaf(x1, w.w, acc1.w);
        acc2.x = fmaf(x2v, w.x, acc2.x); acc2.y = fmaf(x2v, w.y, acc2.y);
        acc2.z = fmaf(x2v, w.z, acc2.z); acc2.w = fmaf(x2v, w.w, acc2.w);
        acc3.x = fmaf(x3, w.x, acc3.x); acc3.y = fmaf(x3, w.y, acc3.y);
        acc3.z = fmaf(x3, w.z, acc3.z); acc3.w = fmaf(x3, w.w, acc3.w);
    }
    float4 a4s = *(const float4*)&a_src[cg * 4];
    float4 a4d = *(const float4*)&a_dst[cg * 4];
    float4 accs[4] = {acc0, acc1, acc2, acc3};
    #pragma unroll
    for (int j = 0; j < 4; j++){
        int n = n0 + ns + 8 * j;
        if (n >= N) continue;
        float4 a = accs[j];
        half4 hv;
        hv.x = (_Float16)a.x; hv.y = (_Float16)a.y;
        hv.z = (_Float16)a.z; hv.w = (_Float16)a.w;
        *(half4*)&h1h[((size_t)n << 7) + (cg << 2)] = hv;
        float vs = a.x * a4s.x + a.y * a4s.y + a.z * a4s.z + a.w * a4s.w;
        float vd = a.x * a4d.x + a.y * a4d.y + a.z * a4d.z + a.w * a4d.w;
        #pragma unroll
        for (int m = 1; m <= 4; m <<= 1){
            vs += __shfl_xor(vs, m, 64);
            vd += __shfl_xor(vd, m, 64);
        }
        if ((cg & 7) == 0){
            int head = cg >> 3;
            asrc1[n * 4 + head] = vs;
            adst1[n * 4 + head] = vd;
        }
    }
}

// ---------------- Aggregation L1: 8 groups x 32 lanes, fp16 half4 gather ----------------
// lane l covers columns 4l..4l+3, all in head l>>3; denominator is PER HEAD.

__launch_bounds__(256)
__global__ void k_agg1(const int* __restrict__ rowptr, const int* __restrict__ csr_src,
                       const float* __restrict__ asrc1, const float* __restrict__ adst1,
                       const _Float16* __restrict__ h1h,
                       const float* __restrict__ b1, float* __restrict__ x2){
    int n = blockIdx.x;
    int t = threadIdx.x;
    int g = t >> 5, l = t & 31, head = l >> 3;
    int start = rowptr[n], end = rowptr[n + 1];
    float adn = adst1[(n << 2) + head];
    float4 acc = {0.f, 0.f, 0.f, 0.f};
    float ssum = 0.f;
    for (int i = start + g; i < end; i += 8){
        int s = csr_src[i];
        float e = asrc1[(s << 2) + head] + adn;
        e = fmaxf(e, NEG_SLOPE * e);
        float w = __expf(e);
        half4 hv = *(const half4*)&h1h[((size_t)s << 7) + (l << 2)];
        ssum += w;
        acc.x = fmaf(w, (float)hv.x, acc.x); acc.y = fmaf(w, (float)hv.y, acc.y);
        acc.z = fmaf(w, (float)hv.z, acc.z); acc.w = fmaf(w, (float)hv.w, acc.w);
    }
    __shared__ float racc[8][128];
    __shared__ float rs[8][4];          // per-(group, head) denominators
    *(float4*)&racc[g][l * 4] = acc;
    if ((l & 7) == 0) rs[g][head] = ssum;
    __syncthreads();
    if (t < 128){
        int h = t >> 5;                 // head of output column t
        float a = 0.f;
        #pragma unroll
        for (int p = 0; p < 8; p++) a += racc[p][t];
        float S = 0.f;
        #pragma unroll
        for (int p = 0; p < 8; p++) S += rs[p][h];
        float o = a / (S + EPSV) + b1[t];
        x2[((size_t)n << 7) + t] = (o > 0.f) ? o : expm1f(o);   // ELU fused
    }
}

// ---------------- GEMM2: h2 = x2 @ W2 (h2 stored fp16), 4-node blocking ----------------

__launch_bounds__(256)
__global__ void k_gemm2(const float* __restrict__ x2, const float* __restrict__ W2,
                        const float* __restrict__ a_src, const float* __restrict__ a_dst,
                        _Float16* __restrict__ h2h, float* __restrict__ asrc2,
                        float* __restrict__ adst2, int N){
    __shared__ float Wl[128 * 32];    // 16 KB
    __shared__ float xl[128 * 128];   // 64 KB
    int t = threadIdx.x;
    int cg = t & 7, ns = t >> 3;      // ns in 0..31
    for (int idx = t; idx < 1024; idx += 256)
        *(float4*)&Wl[idx * 4] = *(const float4*)&W2[idx * 4];
    int n0 = blockIdx.x * 128;
    for (int idx = t; idx < 4096; idx += 256){
        int row = idx >> 5, k4 = idx & 31;
        float4 v = {0.f, 0.f, 0.f, 0.f};
        if (n0 + row < N) v = *(const float4*)&x2[(size_t)(n0 + row) * 128 + k4 * 4];
        *(float4*)&xl[row * 128 + k4 * 4] = v;
    }
    __syncthreads();
    float4 acc0 = {0,0,0,0}, acc1 = {0,0,0,0}, acc2 = {0,0,0,0}, acc3 = {0,0,0,0};
    #pragma unroll 4
    for (int k = 0; k < 128; k++){
        float4 w = *(float4*)&Wl[k * 32 + cg * 4];
        float x0 = xl[(ns      ) * 128 + k];
        float x1 = xl[(ns +  32) * 128 + k];
        float x2v= xl[(ns +  64) * 128 + k];
        float x3 = xl[(ns +  96) * 128 + k];
        acc0.x = fmaf(x0, w.x, acc0.x); acc0.y = fmaf(x0, w.y, acc0.y);
        acc0.z = fmaf(x0, w.z, acc0.z); acc0.w = fmaf(x0, w.w, acc0.w);
        acc1.x = fmaf(x1, w.x, acc1.x); acc1.y = fmaf(x1, w.y, acc1.y);
        acc1.z = fmaf(x1, w.z, acc1.z); acc1.w = fmaf(x1, w.w, acc1.w);
        acc2.x = fmaf(x2v, w.x, acc2.x); acc2.y = fmaf(x2v, w.y, acc2.y);
        acc2.z = fmaf(x2v, w.z, acc2.z); acc2.w = fmaf(x2v, w.w, acc2.w);
        acc3.x = fmaf(x3, w.x, acc3.x); acc3.y = fmaf(x3, w.y, acc3.y);
        acc3.z = fmaf(x3, w.z, acc3.z); acc3.w = fmaf(x3, w.w, acc3.w);
    }
    float4 a4s = *(const float4*)&a_src[cg * 4];
    float4 a4d = *(const float4*)&a_dst[cg * 4];
    float4 accs[4] = {acc0, acc1, acc2, acc3};
    #pragma unroll
    for (int j = 0; j < 4; j++){
        int n = n0 + ns + 32 * j;
        if (n >= N) continue;
        float4 a = accs[j];
        half4 hv;
        hv.x = (_Float16)a.x; hv.y = (_Float16)a.y;
        hv.z = (_Float16)a.z; hv.w = (_Float16)a.w;
        *(half4*)&h2h[((size_t)n << 5) + (cg << 2)] = hv;
        float vs = a.x * a4s.x + a.y * a4s.y + a.z * a4s.z + a.w * a4s.w;
        float vd = a.x * a4d.x + a.y * a4d.y + a.z * a4d.z + a.w * a4d.w;
        #pragma unroll
        for (int m = 1; m <= 4; m <<= 1){
            vs += __shfl_xor(vs, m, 64);
            vd += __shfl_xor(vd, m, 64);
        }
        if (cg == 0){ asrc2[n] = vs; adst2[n] = vd; }
    }
}

// ---------------- Aggregation L2: wave per node, 8 groups x 8 lanes, fp16 gather ----------

__launch_bounds__(256)
__global__ void k_agg2(const int* __restrict__ rowptr, const int* __restrict__ csr_src,
                       const float* __restrict__ asrc2, const float* __restrict__ adst2,
                       const _Float16* __restrict__ h2h,
                       const float* __restrict__ b2, float* __restrict__ out){
    int t = threadIdx.x;
    int n = blockIdx.x * 4 + (t >> 6);
    int lane = t & 63, g = lane >> 3, l = lane & 7;
    int start = rowptr[n], end = rowptr[n + 1];
    float adn = adst2[n];
    float4 acc = {0.f, 0.f, 0.f, 0.f};
    float ssum = 0.f;
    for (int i = start + g; i < end; i += 8){
        int s = csr_src[i];
        float e = asrc2[s] + adn;
        e = fmaxf(e, NEG_SLOPE * e);
        float w = __expf(e);
        half4 hv = *(const half4*)&h2h[((size_t)s << 5) + (l << 2)];
        ssum += w;
        acc.x = fmaf(w, (float)hv.x, acc.x); acc.y = fmaf(w, (float)hv.y, acc.y);
        acc.z = fmaf(w, (float)hv.z, acc.z); acc.w = fmaf(w, (float)hv.w, acc.w);
    }
    #pragma unroll
    for (int m = 8; m <= 32; m <<= 1){
        acc.x += __shfl_xor(acc.x, m, 64);
        acc.y += __shfl_xor(acc.y, m, 64);
        acc.z += __shfl_xor(acc.z, m, 64);
        acc.w += __shfl_xor(acc.w, m, 64);
        ssum  += __shfl_xor(ssum,  m, 64);
    }
    if (g == 0){
        float inv = 1.f / (ssum + EPSV);
        const float4 b4 = *(const float4*)&b2[l * 4];
        float4 o;
        o.x = acc.x * inv + b4.x; o.y = acc.y * inv + b4.y;
        o.z = acc.z * inv + b4.z; o.w = acc.w * inv + b4.w;
        *(float4*)&out[((size_t)n << 5) + l * 4] = o;
    }
}

// ---------------- launch ----------------

extern "C" void kernel_launch(void* const* d_in, const int* in_sizes, int n_in,
                              void* d_out, int out_size, void* d_ws, size_t ws_size,
                              hipStream_t stream){
    const float* x      = (const float*)d_in[0];
    const int*   ei     = (const int*)  d_in[1];
    const float* W1     = (const float*)d_in[2];
    const float* a_src1 = (const float*)d_in[3];
    const float* a_dst1 = (const float*)d_in[4];
    const float* b1     = (const float*)d_in[5];
    const float* W2     = (const float*)d_in[6];
    const float* a_src2 = (const float*)d_in[7];
    const float* a_dst2 = (const float*)d_in[8];
    const float* b2     = (const float*)d_in[9];
    float* out = (float*)d_out;

    int N  = in_sizes[0] / 128;
    int E  = in_sizes[1] / 2;
    int ET = E + N;
    int nScanBlk = (N + 1023) / 1024;
    int G  = (ET + 255) / 256;

    char* ws = (char*)d_ws;
    size_t off = 0;
    auto alloc = [&](size_t bytes) -> char* {
        char* p = ws + off;
        off += (bytes + 255) & ~(size_t)255;
        return p;
    };
    int*      degp    = (int*)     alloc((size_t)NPART * N * 4);
    int*      deg     = (int*)     alloc((size_t)N * 4);
    int*      rowptr  = (int*)     alloc((size_t)(N + 1) * 4);
    int*      bsum    = (int*)     alloc((size_t)nScanBlk * 4);
    int*      rank    = (int*)     alloc((size_t)ET * 4);
    int*      poff    = (int*)     alloc((size_t)NPART * N * 4);
    int*      csr_src = (int*)     alloc((size_t)ET * 4);
    _Float16* h1h     = (_Float16*)alloc((size_t)N * 128 * 2);
    float*    x2      = (float*)   alloc((size_t)N * 128 * 4);
    float*    asrc1   = (float*)   alloc((size_t)N * 4 * 4);
    float*    adst1   = (float*)   alloc((size_t)N * 4 * 4);
    _Float16* h2h     = (_Float16*)alloc((size_t)N * 32 * 2);
    float*    asrc2   = (float*)   alloc((size_t)N * 4);
    float*    adst2   = (float*)   alloc((size_t)N * 4);

    hipMemsetAsync(degp, 0, (size_t)NPART * N * 4, stream);
    hipLaunchKernelGGL(k_hist_rank, dim3(G), dim3(256), 0, stream, ei, E, ET, N, degp, rank);
    hipLaunchKernelGGL(k_combine,   dim3((N + 255) / 256), dim3(256), 0, stream, degp, N, deg, poff);
    hipLaunchKernelGGL(k_scan_blk,  dim3(nScanBlk), dim3(256), 0, stream, deg, N, rowptr, bsum);
    hipLaunchKernelGGL(k_scan_top,  dim3(1),        dim3(64),  0, stream, bsum, nScanBlk);
    hipLaunchKernelGGL(k_finalize,  dim3((N + 255) / 256), dim3(256), 0, stream, bsum, N, ET, rowptr, poff);
    hipLaunchKernelGGL(k_scatter2,  dim3(G), dim3(256), 0, stream, ei, E, ET, N, poff, rank, csr_src);
    hipLaunchKernelGGL(k_gemm1,     dim3((N + 31) / 32), dim3(256), 0, stream, x, W1, a_src1, a_dst1, h1h, asrc1, adst1, N);
    hipLaunchKernelGGL(k_agg1,      dim3(N), dim3(256), 0, stream, rowptr, csr_src, asrc1, adst1, h1h, b1, x2);
    hipLaunchKernelGGL(k_gemm2,     dim3((N + 127) / 128), dim3(256), 0, stream, x2, W2, a_src2, a_dst2, h2h, asrc2, adst2, N);
    hipLaunchKernelGGL(k_agg2,      dim3(N / 4), dim3(256), 0, stream, rowptr, csr_src, asrc2, adst2, h2h, b2, out);
}

// Round 7
// 343.415 us; speedup vs baseline: 2.4563x; 1.1193x over previous
//
#include <hip/hip_runtime.h>
#include <math.h>

#define NEG_SLOPE 0.2f
#define EPSV 1e-16f
#define NPART 16

typedef _Float16 half4 __attribute__((ext_vector_type(4)));
typedef _Float16 half8 __attribute__((ext_vector_type(8)));

// ---------------- CSR build ----------------

// 16-way partitioned histogram; records each edge's rank within (partition,dst).
__global__ void k_hist_rank(const int* __restrict__ ei, int E, int ET, int N,
                            int* __restrict__ degp, int* __restrict__ rank){
    int i = blockIdx.x * 256 + threadIdx.x;
    if (i < ET){
        int d = (i < E) ? ei[E + i] : (i - E);   // self loops appended
        int p = blockIdx.x & (NPART - 1);
        rank[i] = atomicAdd(&degp[p * N + d], 1);
    }
}

// per-node: total degree + exclusive prefix over partitions
__global__ void k_combine(const int* __restrict__ degp, int N,
                          int* __restrict__ deg, int* __restrict__ poff){
    int n = blockIdx.x * 256 + threadIdx.x;
    if (n < N){
        int s = 0;
        #pragma unroll
        for (int p = 0; p < NPART; p++){
            int t = degp[p * N + n];
            poff[p * N + n] = s;
            s += t;
        }
        deg[n] = s;
    }
}

// hierarchical scan: blocks of 1024 elems -> top scan -> fixup
__global__ void k_scan_blk(const int* __restrict__ deg, int N,
                           int* __restrict__ rowptr, int* __restrict__ bsum){
    int b = blockIdx.x, t = threadIdx.x;
    int base = b * 1024 + t * 4;
    int v[4];
    #pragma unroll
    for (int j = 0; j < 4; j++) v[j] = (base + j < N) ? deg[base + j] : 0;
    int s = v[0] + v[1] + v[2] + v[3];
    int lane = t & 63, wid = t >> 6;
    int x = s;
    #pragma unroll
    for (int off = 1; off < 64; off <<= 1){
        int y = __shfl_up(x, off, 64);
        if (lane >= off) x += y;
    }
    __shared__ int ws[4];
    if (lane == 63) ws[wid] = x;
    __syncthreads();
    int woff = 0;
    for (int w = 0; w < wid; w++) woff += ws[w];
    int run = woff + x - s;
    #pragma unroll
    for (int j = 0; j < 4; j++){
        if (base + j < N) rowptr[base + j] = run;
        run += v[j];
    }
    if (t == 255) bsum[b] = woff + x;
}

__global__ void k_scan_top(int* bsum, int nb){
    int t = threadIdx.x;
    int v = (t < nb) ? bsum[t] : 0;
    int x = v;
    #pragma unroll
    for (int off = 1; off < 64; off <<= 1){
        int y = __shfl_up(x, off, 64);
        if (t >= off) x += y;
    }
    if (t < nb) bsum[t] = x - v;   // exclusive
}

// rowptr += block offset; poff[p][n] += final rowptr[n]
__global__ void k_finalize(const int* __restrict__ bsum, int N, int ET,
                           int* __restrict__ rowptr, int* __restrict__ poff){
    int n = blockIdx.x * 256 + threadIdx.x;
    if (n < N){
        int r = rowptr[n] + bsum[n >> 10];
        rowptr[n] = r;
        #pragma unroll
        for (int p = 0; p < NPART; p++) poff[p * N + n] += r;
    }
    if (n == 0) rowptr[N] = ET;
}

// atomic-free scatter (src only; dst implicit via rowptr ranges)
__launch_bounds__(256)
__global__ void k_scatter2(const int* __restrict__ ei, int E, int ET, int N,
                           const int* __restrict__ poff, const int* __restrict__ rank,
                           int* __restrict__ csr_src){
    int i = blockIdx.x * 256 + threadIdx.x;
    if (i >= ET) return;
    int s, d;
    if (i < E){ s = ei[i]; d = ei[E + i]; } else { s = i - E; d = s; }
    int p = blockIdx.x & (NPART - 1);
    csr_src[poff[p * N + d] + rank[i]] = s;
}

// ---------------- GEMM1: h1 = x @ W1 (h1 stored fp16), 4-node register blocking ----

__launch_bounds__(256)
__global__ void k_gemm1(const float* __restrict__ x, const float* __restrict__ W1,
                        const float* __restrict__ a_src, const float* __restrict__ a_dst,
                        _Float16* __restrict__ h1h, float* __restrict__ asrc1,
                        float* __restrict__ adst1, int N){
    __shared__ float Wl[128 * 128];   // 64 KB, [k][col]
    __shared__ float xl[32 * 128];    // 16 KB
    int t = threadIdx.x;
    int cg = t & 31, ns = t >> 5;     // ns in 0..7
    for (int idx = t; idx < 4096; idx += 256)
        *(float4*)&Wl[idx * 4] = *(const float4*)&W1[idx * 4];
    int n0 = blockIdx.x * 32;
    for (int idx = t; idx < 1024; idx += 256){
        int row = idx >> 5, k4 = idx & 31;
        float4 v = {0.f, 0.f, 0.f, 0.f};
        if (n0 + row < N) v = *(const float4*)&x[(size_t)(n0 + row) * 128 + k4 * 4];
        *(float4*)&xl[row * 128 + k4 * 4] = v;
    }
    __syncthreads();
    float4 acc0 = {0,0,0,0}, acc1 = {0,0,0,0}, acc2 = {0,0,0,0}, acc3 = {0,0,0,0};
    #pragma unroll 4
    for (int k = 0; k < 128; k++){
        float4 w = *(float4*)&Wl[k * 128 + cg * 4];
        float x0 = xl[(ns     ) * 128 + k];
        float x1 = xl[(ns +  8) * 128 + k];
        float x2v= xl[(ns + 16) * 128 + k];
        float x3 = xl[(ns + 24) * 128 + k];
        acc0.x = fmaf(x0, w.x, acc0.x); acc0.y = fmaf(x0, w.y, acc0.y);
        acc0.z = fmaf(x0, w.z, acc0.z); acc0.w = fmaf(x0, w.w, acc0.w);
        acc1.x = fmaf(x1, w.x, acc1.x); acc1.y = fmaf(x1, w.y, acc1.y);
        acc1.z = fmaf(x1, w.z, acc1.z); acc1.w = fmaf(x1, w.w, acc1.w);
        acc2.x = fmaf(x2v, w.x, acc2.x); acc2.y = fmaf(x2v, w.y, acc2.y);
        acc2.z = fmaf(x2v, w.z, acc2.z); acc2.w = fmaf(x2v, w.w, acc2.w);
        acc3.x = fmaf(x3, w.x, acc3.x); acc3.y = fmaf(x3, w.y, acc3.y);
        acc3.z = fmaf(x3, w.z, acc3.z); acc3.w = fmaf(x3, w.w, acc3.w);
    }
    float4 a4s = *(const float4*)&a_src[cg * 4];
    float4 a4d = *(const float4*)&a_dst[cg * 4];
    float4 accs[4] = {acc0, acc1, acc2, acc3};
    #pragma unroll
    for (int j = 0; j < 4; j++){
        int n = n0 + ns + 8 * j;
        if (n >= N) continue;
        float4 a = accs[j];
        half4 hv;
        hv.x = (_Float16)a.x; hv.y = (_Float16)a.y;
        hv.z = (_Float16)a.z; hv.w = (_Float16)a.w;
        *(half4*)&h1h[((size_t)n << 7) + (cg << 2)] = hv;
        float vs = a.x * a4s.x + a.y * a4s.y + a.z * a4s.z + a.w * a4s.w;
        float vd = a.x * a4d.x + a.y * a4d.y + a.z * a4d.z + a.w * a4d.w;
        #pragma unroll
        for (int m = 1; m <= 4; m <<= 1){
            vs += __shfl_xor(vs, m, 64);
            vd += __shfl_xor(vd, m, 64);
        }
        if ((cg & 7) == 0){
            int head = cg >> 3;
            asrc1[n * 4 + head] = vs;
            adst1[n * 4 + head] = vd;
        }
    }
}

// ---------------- Aggregation L1: wave per node, 4 groups x 16 lanes, half8 gather ----
// lane l (0..15) covers cols 8l..8l+7 (head = l>>2); unroll-2 dual accumulators;
// shuffle-only reduction (xor 16, 32) — no LDS, no syncthreads.

__launch_bounds__(256)
__global__ void k_agg1(const int* __restrict__ rowptr, const int* __restrict__ csr_src,
                       const float* __restrict__ asrc1, const float* __restrict__ adst1,
                       const _Float16* __restrict__ h1h,
                       const float* __restrict__ b1, float* __restrict__ x2){
    int t = threadIdx.x;
    int n = blockIdx.x * 4 + (t >> 6);
    int lane = t & 63, g = lane >> 4, l = lane & 15, head = l >> 2;
    int start = rowptr[n], end = rowptr[n + 1];
    float adn = adst1[(n << 2) + head];
    float rA[8] = {0,0,0,0,0,0,0,0}, rB[8] = {0,0,0,0,0,0,0,0};
    float sA = 0.f, sB = 0.f;
    int i = start + g;
    for (; i + 4 < end; i += 8){
        int s0 = csr_src[i];
        int s1 = csr_src[i + 4];
        float e0 = asrc1[(s0 << 2) + head] + adn;
        float e1 = asrc1[(s1 << 2) + head] + adn;
        e0 = fmaxf(e0, NEG_SLOPE * e0);
        e1 = fmaxf(e1, NEG_SLOPE * e1);
        float w0 = __expf(e0);
        float w1 = __expf(e1);
        half8 h0 = *(const half8*)&h1h[((size_t)s0 << 7) + (l << 3)];
        half8 h1v = *(const half8*)&h1h[((size_t)s1 << 7) + (l << 3)];
        sA += w0; sB += w1;
        #pragma unroll
        for (int j = 0; j < 8; j++){
            rA[j] = fmaf(w0, (float)h0[j], rA[j]);
            rB[j] = fmaf(w1, (float)h1v[j], rB[j]);
        }
    }
    if (i < end){
        int s0 = csr_src[i];
        float e0 = asrc1[(s0 << 2) + head] + adn;
        e0 = fmaxf(e0, NEG_SLOPE * e0);
        float w0 = __expf(e0);
        half8 h0 = *(const half8*)&h1h[((size_t)s0 << 7) + (l << 3)];
        sA += w0;
        #pragma unroll
        for (int j = 0; j < 8; j++) rA[j] = fmaf(w0, (float)h0[j], rA[j]);
    }
    float r[9];
    #pragma unroll
    for (int j = 0; j < 8; j++) r[j] = rA[j] + rB[j];
    r[8] = sA + sB;
    #pragma unroll
    for (int m = 16; m <= 32; m <<= 1)
        #pragma unroll
        for (int j = 0; j < 9; j++) r[j] += __shfl_xor(r[j], m, 64);
    if (g == 0){
        float inv = 1.f / (r[8] + EPSV);
        float o[8];
        #pragma unroll
        for (int j = 0; j < 8; j++){
            float v = r[j] * inv + b1[l * 8 + j];
            o[j] = (v > 0.f) ? v : expm1f(v);   // ELU fused
        }
        float4 o0 = {o[0], o[1], o[2], o[3]};
        float4 o1 = {o[4], o[5], o[6], o[7]};
        *(float4*)&x2[((size_t)n << 7) + (l << 3)]     = o0;
        *(float4*)&x2[((size_t)n << 7) + (l << 3) + 4] = o1;
    }
}

// ---------------- GEMM2: h2 = x2 @ W2 (h2 stored fp16), 4-node blocking ----------------

__launch_bounds__(256)
__global__ void k_gemm2(const float* __restrict__ x2, const float* __restrict__ W2,
                        const float* __restrict__ a_src, const float* __restrict__ a_dst,
                        _Float16* __restrict__ h2h, float* __restrict__ asrc2,
                        float* __restrict__ adst2, int N){
    __shared__ float Wl[128 * 32];    // 16 KB
    __shared__ float xl[128 * 128];   // 64 KB
    int t = threadIdx.x;
    int cg = t & 7, ns = t >> 3;      // ns in 0..31
    for (int idx = t; idx < 1024; idx += 256)
        *(float4*)&Wl[idx * 4] = *(const float4*)&W2[idx * 4];
    int n0 = blockIdx.x * 128;
    for (int idx = t; idx < 4096; idx += 256){
        int row = idx >> 5, k4 = idx & 31;
        float4 v = {0.f, 0.f, 0.f, 0.f};
        if (n0 + row < N) v = *(const float4*)&x2[(size_t)(n0 + row) * 128 + k4 * 4];
        *(float4*)&xl[row * 128 + k4 * 4] = v;
    }
    __syncthreads();
    float4 acc0 = {0,0,0,0}, acc1 = {0,0,0,0}, acc2 = {0,0,0,0}, acc3 = {0,0,0,0};
    #pragma unroll 4
    for (int k = 0; k < 128; k++){
        float4 w = *(float4*)&Wl[k * 32 + cg * 4];
        float x0 = xl[(ns      ) * 128 + k];
        float x1 = xl[(ns +  32) * 128 + k];
        float x2v= xl[(ns +  64) * 128 + k];
        float x3 = xl[(ns +  96) * 128 + k];
        acc0.x = fmaf(x0, w.x, acc0.x); acc0.y = fmaf(x0, w.y, acc0.y);
        acc0.z = fmaf(x0, w.z, acc0.z); acc0.w = fmaf(x0, w.w, acc0.w);
        acc1.x = fmaf(x1, w.x, acc1.x); acc1.y = fmaf(x1, w.y, acc1.y);
        acc1.z = fmaf(x1, w.z, acc1.z); acc1.w = fmaf(x1, w.w, acc1.w);
        acc2.x = fmaf(x2v, w.x, acc2.x); acc2.y = fmaf(x2v, w.y, acc2.y);
        acc2.z = fmaf(x2v, w.z, acc2.z); acc2.w = fmaf(x2v, w.w, acc2.w);
        acc3.x = fmaf(x3, w.x, acc3.x); acc3.y = fmaf(x3, w.y, acc3.y);
        acc3.z = fmaf(x3, w.z, acc3.z); acc3.w = fmaf(x3, w.w, acc3.w);
    }
    float4 a4s = *(const float4*)&a_src[cg * 4];
    float4 a4d = *(const float4*)&a_dst[cg * 4];
    float4 accs[4] = {acc0, acc1, acc2, acc3};
    #pragma unroll
    for (int j = 0; j < 4; j++){
        int n = n0 + ns + 32 * j;
        if (n >= N) continue;
        float4 a = accs[j];
        half4 hv;
        hv.x = (_Float16)a.x; hv.y = (_Float16)a.y;
        hv.z = (_Float16)a.z; hv.w = (_Float16)a.w;
        *(half4*)&h2h[((size_t)n << 5) + (cg << 2)] = hv;
        float vs = a.x * a4s.x + a.y * a4s.y + a.z * a4s.z + a.w * a4s.w;
        float vd = a.x * a4d.x + a.y * a4d.y + a.z * a4d.z + a.w * a4d.w;
        #pragma unroll
        for (int m = 1; m <= 4; m <<= 1){
            vs += __shfl_xor(vs, m, 64);
            vd += __shfl_xor(vd, m, 64);
        }
        if (cg == 0){ asrc2[n] = vs; adst2[n] = vd; }
    }
}

// ---------------- Aggregation L2: wave per node, 8 groups x 8 lanes, unroll-2 ----------

__launch_bounds__(256)
__global__ void k_agg2(const int* __restrict__ rowptr, const int* __restrict__ csr_src,
                       const float* __restrict__ asrc2, const float* __restrict__ adst2,
                       const _Float16* __restrict__ h2h,
                       const float* __restrict__ b2, float* __restrict__ out){
    int t = threadIdx.x;
    int n = blockIdx.x * 4 + (t >> 6);
    int lane = t & 63, g = lane >> 3, l = lane & 7;
    int start = rowptr[n], end = rowptr[n + 1];
    float adn = adst2[n];
    float4 aA = {0,0,0,0}, aB = {0,0,0,0};
    float sA = 0.f, sB = 0.f;
    int i = start + g;
    for (; i + 8 < end; i += 16){
        int s0 = csr_src[i];
        int s1 = csr_src[i + 8];
        float e0 = asrc2[s0] + adn;
        float e1 = asrc2[s1] + adn;
        e0 = fmaxf(e0, NEG_SLOPE * e0);
        e1 = fmaxf(e1, NEG_SLOPE * e1);
        float w0 = __expf(e0);
        float w1 = __expf(e1);
        half4 h0 = *(const half4*)&h2h[((size_t)s0 << 5) + (l << 2)];
        half4 h1v = *(const half4*)&h2h[((size_t)s1 << 5) + (l << 2)];
        sA += w0; sB += w1;
        aA.x = fmaf(w0, (float)h0.x, aA.x); aA.y = fmaf(w0, (float)h0.y, aA.y);
        aA.z = fmaf(w0, (float)h0.z, aA.z); aA.w = fmaf(w0, (float)h0.w, aA.w);
        aB.x = fmaf(w1, (float)h1v.x, aB.x); aB.y = fmaf(w1, (float)h1v.y, aB.y);
        aB.z = fmaf(w1, (float)h1v.z, aB.z); aB.w = fmaf(w1, (float)h1v.w, aB.w);
    }
    if (i < end){
        int s0 = csr_src[i];
        float e0 = asrc2[s0] + adn;
        e0 = fmaxf(e0, NEG_SLOPE * e0);
        float w0 = __expf(e0);
        half4 h0 = *(const half4*)&h2h[((size_t)s0 << 5) + (l << 2)];
        sA += w0;
        aA.x = fmaf(w0, (float)h0.x, aA.x); aA.y = fmaf(w0, (float)h0.y, aA.y);
        aA.z = fmaf(w0, (float)h0.z, aA.z); aA.w = fmaf(w0, (float)h0.w, aA.w);
    }
    float4 acc = {aA.x + aB.x, aA.y + aB.y, aA.z + aB.z, aA.w + aB.w};
    float ssum = sA + sB;
    #pragma unroll
    for (int m = 8; m <= 32; m <<= 1){
        acc.x += __shfl_xor(acc.x, m, 64);
        acc.y += __shfl_xor(acc.y, m, 64);
        acc.z += __shfl_xor(acc.z, m, 64);
        acc.w += __shfl_xor(acc.w, m, 64);
        ssum  += __shfl_xor(ssum,  m, 64);
    }
    if (g == 0){
        float inv = 1.f / (ssum + EPSV);
        const float4 b4 = *(const float4*)&b2[l * 4];
        float4 o;
        o.x = acc.x * inv + b4.x; o.y = acc.y * inv + b4.y;
        o.z = acc.z * inv + b4.z; o.w = acc.w * inv + b4.w;
        *(float4*)&out[((size_t)n << 5) + l * 4] = o;
    }
}

// ---------------- launch ----------------

extern "C" void kernel_launch(void* const* d_in, const int* in_sizes, int n_in,
                              void* d_out, int out_size, void* d_ws, size_t ws_size,
                              hipStream_t stream){
    const float* x      = (const float*)d_in[0];
    const int*   ei     = (const int*)  d_in[1];
    const float* W1     = (const float*)d_in[2];
    const float* a_src1 = (const float*)d_in[3];
    const float* a_dst1 = (const float*)d_in[4];
    const float* b1     = (const float*)d_in[5];
    const float* W2     = (const float*)d_in[6];
    const float* a_src2 = (const float*)d_in[7];
    const float* a_dst2 = (const float*)d_in[8];
    const float* b2     = (const float*)d_in[9];
    float* out = (float*)d_out;

    int N  = in_sizes[0] / 128;
    int E  = in_sizes[1] / 2;
    int ET = E + N;
    int nScanBlk = (N + 1023) / 1024;
    int G  = (ET + 255) / 256;

    char* ws = (char*)d_ws;
    size_t off = 0;
    auto alloc = [&](size_t bytes) -> char* {
        char* p = ws + off;
        off += (bytes + 255) & ~(size_t)255;
        return p;
    };
    int*      degp    = (int*)     alloc((size_t)NPART * N * 4);
    int*      deg     = (int*)     alloc((size_t)N * 4);
    int*      rowptr  = (int*)     alloc((size_t)(N + 1) * 4);
    int*      bsum    = (int*)     alloc((size_t)nScanBlk * 4);
    int*      rank    = (int*)     alloc((size_t)ET * 4);
    int*      poff    = (int*)     alloc((size_t)NPART * N * 4);
    int*      csr_src = (int*)     alloc((size_t)ET * 4);
    _Float16* h1h     = (_Float16*)alloc((size_t)N * 128 * 2);
    float*    x2      = (float*)   alloc((size_t)N * 128 * 4);
    float*    asrc1   = (float*)   alloc((size_t)N * 4 * 4);
    float*    adst1   = (float*)   alloc((size_t)N * 4 * 4);
    _Float16* h2h     = (_Float16*)alloc((size_t)N * 32 * 2);
    float*    asrc2   = (float*)   alloc((size_t)N * 4);
    float*    adst2   = (float*)   alloc((size_t)N * 4);

    hipMemsetAsync(degp, 0, (size_t)NPART * N * 4, stream);
    hipLaunchKernelGGL(k_hist_rank, dim3(G), dim3(256), 0, stream, ei, E, ET, N, degp, rank);
    hipLaunchKernelGGL(k_combine,   dim3((N + 255) / 256), dim3(256), 0, stream, degp, N, deg, poff);
    hipLaunchKernelGGL(k_scan_blk,  dim3(nScanBlk), dim3(256), 0, stream, deg, N, rowptr, bsum);
    hipLaunchKernelGGL(k_scan_top,  dim3(1),        dim3(64),  0, stream, bsum, nScanBlk);
    hipLaunchKernelGGL(k_finalize,  dim3((N + 255) / 256), dim3(256), 0, stream, bsum, N, ET, rowptr, poff);
    hipLaunchKernelGGL(k_scatter2,  dim3(G), dim3(256), 0, stream, ei, E, ET, N, poff, rank, csr_src);
    hipLaunchKernelGGL(k_gemm1,     dim3((N + 31) / 32), dim3(256), 0, stream, x, W1, a_src1, a_dst1, h1h, asrc1, adst1, N);
    hipLaunchKernelGGL(k_agg1,      dim3(N / 4), dim3(256), 0, stream, rowptr, csr_src, asrc1, adst1, h1h, b1, x2);
    hipLaunchKernelGGL(k_gemm2,     dim3((N + 127) / 128), dim3(256), 0, stream, x2, W2, a_src2, a_dst2, h2h, asrc2, adst2, N);
    hipLaunchKernelGGL(k_agg2,      dim3(N / 4), dim3(256), 0, stream, rowptr, csr_src, asrc2, adst2, h2h, b2, out);
}